// Round 7
// baseline (1005.013 us; speedup 1.0000x reference)
//
#include <hip/hip_runtime.h>
#include <stdint.h>
#include <math.h>

#define N_B 4
#define T_S 4096
#define D_M 1024
#define H_M 1536
#define NT  (N_B * T_S)   // 16384
#define G2  (2 * H_M)     // 3072
#define LCH 64            // timesteps per chunk
#define NCH 64            // chunks (LCH*NCH == T_S)

typedef __attribute__((ext_vector_type(8))) short short8;
typedef __attribute__((ext_vector_type(4))) float floatx4;

__device__ __forceinline__ unsigned short f2bf(float f) {
  unsigned u = __float_as_uint(f);
  u += 0x7fff + ((u >> 16) & 1);            // RNE
  return (unsigned short)(u >> 16);
}
__device__ __forceinline__ float bf2f(unsigned short u) {
  return __uint_as_float(((unsigned)u) << 16);
}
__device__ __forceinline__ float bf_lo(unsigned p) { return __uint_as_float(p << 16); }
__device__ __forceinline__ float bf_hi(unsigned p) { return __uint_as_float(p & 0xffff0000u); }
__device__ __forceinline__ unsigned bf_pack(float lo, float hi) {
  return ((unsigned)f2bf(lo)) | (((unsigned)f2bf(hi)) << 16);
}
__device__ __forceinline__ float sigmoidf_(float x) { return 1.f / (1.f + __expf(-x)); }
__device__ __forceinline__ float softplusf_(float x) {
  return (x > 20.f) ? x : log1pf(__expf(x));
}
__device__ __forceinline__ float geluf_(float x) {
  return 0.5f * x * (1.f + erff(x * 0.70710678118654752f));
}

// ---------------- zero-fill fallback (diagnostic if ws_size too small) ----------------
__global__ void zero_out(float* __restrict__ out, int n) {
  int i = blockIdx.x * 256 + threadIdx.x;
  if (i < n) out[i] = 0.f;
}

// ---------------- fused f32 -> bf16 conversion of x, Win, Wg (one launch) ----------------
#define N4_X   (NT * D_M / 4)          // 4,194,304
#define N4_WIN (G2 * D_M / 4)          //   786,432
#define N4_WG  (G2 * H_M / 4)          // 1,179,648
__global__ void cvt3_bf16(const float* __restrict__ x, unsigned short* __restrict__ x16,
                          const float* __restrict__ win, unsigned short* __restrict__ win16,
                          const float* __restrict__ wg, unsigned short* __restrict__ wg16) {
  int i = blockIdx.x * 256 + threadIdx.x;
  const float* in; unsigned short* out;
  if (i < N4_X)                { in = x;   out = x16; }
  else if (i < N4_X + N4_WIN)  { in = win; out = win16; i -= N4_X; }
  else if (i < N4_X + N4_WIN + N4_WG) { in = wg; out = wg16; i -= N4_X + N4_WIN; }
  else return;
  float4 v = ((const float4*)in)[i];
  ushort4 o;
  o.x = f2bf(v.x); o.y = f2bf(v.y); o.z = f2bf(v.z); o.w = f2bf(v.w);
  ((ushort4*)out)[i] = o;
}

__global__ void cvt_bf16(const float* __restrict__ in, unsigned short* __restrict__ out, int n4) {
  int i = blockIdx.x * 256 + threadIdx.x;
  if (i >= n4) return;
  float4 v = ((const float4*)in)[i];
  ushort4 o;
  o.x = f2bf(v.x); o.y = f2bf(v.y); o.z = f2bf(v.z); o.w = f2bf(v.w);
  ((ushort4*)out)[i] = o;
}

// ---------------- bf16 MFMA GEMM, 256x256 tile, A-from-global / B-only-LDS ------------
// C[m,n] = sum_k A[m,k]*B[n,k] (+bias[n]).  512 threads = 8 waves (2 Mx4 N), BK=64.
// r5 post-mortem arithmetic: per K-tile per CU, MFMA = 2060 cy (matrix pipe) but LDS
// machine = 192KB reads (A read 4x, B 2x) + 64KB writes ~= 2800 cy @ 85 B/cy -> measured
// tile time 4970 cy == serial sum; the r2-r4 structure is LDS-BW-bound (machine cap ~73%
// MfmaUtil even with perfect overlap). r6: remove A from LDS entirely.
//  - A fragments are per-lane 16B contiguous at A[row][k0+kh*32+kq*8] -> plain global
//    short8 loads (global_load_dwordx4, 16 rows x 64B lines per wave instr). The 4x
//    cross-wave re-read hits per-CU L1 (8KB/phase working set). Compiler tracks af
//    dependencies exactly (plain loads), so no manual vmcnt for A.
//  - LDS carries only B: Bs[2 buf][2 half][128 x 64] = 64 KiB; staging/swizzle verbatim
//    from r4 (0 conflicts measured). LDS traffic/tile = 32KB write + 64KB read ~= 1100 cy
//    << 2060 cy MFMA -> MFMA-pipe-bound if overlap works.
//  - ONE barrier + ONE vmcnt(0) per tile (boundary): drains B(t+1) staging (issued P1/P2
//    of tile t, ~2-3 phases of flight >= HBM latency) and the prefetched af0 (issued P4,
//    mostly landed). No other fences: compiler schedules freely inside the tile.
//  - phases: P1 {bfr 8 ds_read + af1 load + stage Bh0' + 16 MFMA(af0)}, P2 {af2 + stage
//    Bh1' + MFMA(af1)}, P3 {af3 + MFMA(af2)}, P4 {af0(next tile) + MFMA(af3)}. af sets
//    are statically named (rule #20) and single-phase-lived -> allocator overlaps them.
// Bank swizzle (B, r4-proven): phys 16B-group = (kh*4+kq) ^ (fr&7) on reads; global
// source pre-swizzled g=(tid&7)^((tid>>3)&7), LDS dest linear (rule #21).
// XCD swizzle (r1-proven: FETCH 234->141 MB): bijective, nwg%8==0 for all shapes.
#define TM 256
#define TN 256

__device__ __forceinline__ void stage16(const unsigned short* g, unsigned short* l) {
  __builtin_amdgcn_global_load_lds((__attribute__((address_space(1))) void*)g,
                                   (__attribute__((address_space(3))) void*)l, 16, 0, 0);
}

template<bool BIAS, bool OUT_BF16, bool SPLIT>
__global__ __launch_bounds__(512, 2)
void gemm_bt8(const unsigned short* __restrict__ A,
              const unsigned short* __restrict__ B,
              void* __restrict__ Cv, void* __restrict__ Cv2,
              const float* __restrict__ bias,
              int N, int K) {
  __shared__ __align__(16) unsigned short Bs[2][2][8192];   // 64 KiB, B only
  const int tid  = threadIdx.x;
  const int lane = tid & 63;
  const int wave = tid >> 6;
  const int wr = wave >> 2;                  // 0..1  (M half of tile)
  const int wc = wave & 3;                   // 0..3  (N quarter of tile)

  // bijective XCD-aware block swizzle (nwg % 8 == 0 for all shapes used)
  const int gx  = gridDim.x;
  const int nwg = gx * gridDim.y;
  const int bid = blockIdx.y * gx + blockIdx.x;
  const int cpx = nwg >> 3;
  const int swz = (bid & 7) * cpx + (bid >> 3);
  const int bm = (swz / gx) * TM;
  const int bn = (swz % gx) * TN;

  floatx4 acc[8][4];
#pragma unroll
  for (int i = 0; i < 8; i++)
#pragma unroll
    for (int j = 0; j < 4; j++)
      acc[i][j] = (floatx4){0.f, 0.f, 0.f, 0.f};

  // ---- B staging (r4 verbatim): one half = 128 rows x 64 k = 1024 x 16B chunks;
  // thread does c=tid, tid+512. chunk c -> row r=c>>3, phys slot sl=c&7; fetches global
  // k-group g = sl ^ (r&7) = (tid&7)^((tid>>3)&7).
  const int r0_ = tid >> 3;                  // 0..63
  const int g8  = ((tid & 7) ^ (r0_ & 7)) * 8;
  const unsigned short* Bg[2][2];            // [half][u]
#pragma unroll
  for (int h = 0; h < 2; ++h)
#pragma unroll
    for (int u = 0; u < 2; ++u)
      Bg[h][u] = B + (size_t)(bn + h * 128 + r0_ + 64 * u) * K + g8;
  const int ldd = tid * 8;

#define STAGE_B(bu, h, kb) do { \
    stage16(Bg[h][0] + (kb), &Bs[bu][h][ldd]); \
    stage16(Bg[h][1] + (kb), &Bs[bu][h][ldd + 4096]); } while (0)

  // ---- fragment addressing: lane (fr, kq); B phys 16B-group = (kh*4+kq) ^ (fr&7)
  const int fr = lane & 15;
  const int kq = lane >> 4;
  const int e8 = fr & 7;
  const int px0 = (kq ^ e8) * 8;             // kh0
  const int px1 = ((4 + kq) ^ e8) * 8;       // kh1
  const int brow = ((wc & 1) * 64 + fr) * 64;   // + j*16*64
  // A per-lane global base: row = bm + wr*128 + fr, k = kq*8
  const unsigned short* gA = A + (size_t)(bm + wr * 128 + fr) * K + kq * 8;

#define LOAD_AF(dst, mq, kb) do { \
    _Pragma("unroll") \
    for (int ii = 0; ii < 2; ++ii) { \
      const unsigned short* ap = gA + (size_t)((mq) * 32 + ii * 16) * K + (kb); \
      dst[ii][0] = *(const short8*)(ap); \
      dst[ii][1] = *(const short8*)(ap + 32); \
    } } while (0)

#define MFMA_Q(base, set) do { \
    __builtin_amdgcn_s_setprio(1); \
    _Pragma("unroll") \
    for (int kh = 0; kh < 2; ++kh) \
      _Pragma("unroll") \
      for (int ii = 0; ii < 2; ++ii) \
        _Pragma("unroll") \
        for (int j = 0; j < 4; ++j) \
          acc[(base) + ii][j] = __builtin_amdgcn_mfma_f32_16x16x32_bf16( \
              set[ii][kh], bfr[j][kh], acc[(base) + ii][j], 0, 0, 0); \
    __builtin_amdgcn_s_setprio(0); } while (0)

  const int nt = K >> 6;
  short8 af0[2][2], af1[2][2], af2[2][2], af3[2][2], bfr[4][2];

  // prologue: B(0) -> buf0; af for tile0 P1
  STAGE_B(0, 0, 0); STAGE_B(0, 1, 0);
  LOAD_AF(af0, 0, 0);

  for (int t = 0; t < nt; ++t) {
    const int par = t & 1;
    const int dn  = par ^ 1;
    const int k0  = t << 6;
    const int kn1 = k0 + 64;
    const bool s1 = (t + 1 < nt);

    // boundary: drain B(t) staging (and the af0 prefetch); single barrier per tile.
    asm volatile("s_waitcnt vmcnt(0)" ::: "memory");
    __builtin_amdgcn_s_barrier();

    const unsigned short* Bb = &Bs[par][wc >> 1][0];

    // ---- P1: all B frags + af1 prefetch + stage Bh0(t+1) + MFMA quadrant 0 (af0) ----
#pragma unroll
    for (int j = 0; j < 4; ++j) {
      bfr[j][0] = *(const short8*)(Bb + brow + j * 1024 + px0);
      bfr[j][1] = *(const short8*)(Bb + brow + j * 1024 + px1);
    }
    LOAD_AF(af1, 1, k0);
    if (s1) STAGE_B(dn, 0, kn1);
    MFMA_Q(0, af0);

    // ---- P2: af2 prefetch + stage Bh1(t+1) + MFMA quadrant 1 (af1) ----
    LOAD_AF(af2, 2, k0);
    if (s1) STAGE_B(dn, 1, kn1);
    MFMA_Q(2, af1);

    // ---- P3: af3 prefetch + MFMA quadrant 2 (af2) ----
    LOAD_AF(af3, 3, k0);
    MFMA_Q(4, af2);

    // ---- P4: af0(next tile P1) prefetch + MFMA quadrant 3 (af3) ----
    if (s1) LOAD_AF(af0, 0, kn1);
    MFMA_Q(6, af3);
  }
#undef STAGE_B
#undef LOAD_AF
#undef MFMA_Q

  // C/D layout (m89-verified): col = lane&15, row = (lane>>4)*4 + reg
  // acc[i][j] rows = bm + wr*128 + i*16. stores row-major (j innermost): 64B C-line
  // halves issued back-to-back (r2-proven, WRITE_SIZE == output size).
  const int half  = SPLIT ? (N >> 1) : N;
  const bool hi   = SPLIT && (bn >= half);
  void* Cb        = hi ? Cv2 : Cv;
  const int coff  = hi ? half : 0;
  const int cn = lane & 15;
  const int rb = (lane >> 4) * 4;
  float bv[4];
#pragma unroll
  for (int j = 0; j < 4; ++j)
    bv[j] = BIAS ? bias[bn + wc * 64 + j * 16 + cn] : 0.f;
  const int col0 = bn + wc * 64 + cn - coff;
#pragma unroll
  for (int i = 0; i < 8; ++i) {
    const int row0 = bm + wr * 128 + i * 16 + rb;
#pragma unroll
    for (int r = 0; r < 4; ++r) {
      const size_t rowb = (size_t)(row0 + r) * half + col0;
#pragma unroll
      for (int j = 0; j < 4; ++j) {
        float v = acc[i][j][r] + bv[j];
        if (OUT_BF16) ((unsigned short*)Cb)[rowb + j * 16] = f2bf(v);
        else          ((float*)Cb)[rowb + j * 16] = v;
      }
    }
  }
}

// ---------------- depthwise causal conv (K=4) + bias, 2 channels/thread ----------------
__global__ void conv_dw(const unsigned int* __restrict__ xbpre2, const float* __restrict__ cw,
                        const float* __restrict__ cb, unsigned int* __restrict__ xbc2) {
  int i0 = blockIdx.x * 256 + threadIdx.x;       // pair index, 0..H_M/2-1
  int t = blockIdx.y;
  size_t nt = (size_t)blockIdx.z * T_S + t;
  const int h = 2 * i0;
  const float4 wa = ((const float4*)cw)[h];      // taps for channel h
  const float4 wb = ((const float4*)cw)[h + 1];  // taps for channel h+1
  const float2 cb2 = ((const float2*)cb)[i0];
  size_t base = nt * (H_M / 2) + i0;
  unsigned p0 = xbpre2[base];
  float aa = cb2.x + wa.w * bf_lo(p0);
  float ab = cb2.y + wb.w * bf_hi(p0);
  if (t >= 1) { unsigned p = xbpre2[base - H_M / 2];
    aa += wa.z * bf_lo(p); ab += wb.z * bf_hi(p); }
  if (t >= 2) { unsigned p = xbpre2[base - 2 * (size_t)(H_M / 2)];
    aa += wa.y * bf_lo(p); ab += wb.y * bf_hi(p); }
  if (t >= 3) { unsigned p = xbpre2[base - 3 * (size_t)(H_M / 2)];
    aa += wa.x * bf_lo(p); ab += wb.x * bf_hi(p); }
  xbc2[base] = bf_pack(aa, ab);
}

// ---------------- chunked linear scan (2 channels/thread) ----------------
__global__ void scan_A(const unsigned int* __restrict__ fg2, const unsigned int* __restrict__ xbc2,
                       const float* __restrict__ fb,
                       float2* __restrict__ cA2, float2* __restrict__ cS2) {
  int i0 = blockIdx.x * 256 + threadIdx.x;       // pair index
  int ch = blockIdx.y;
  int n = blockIdx.z;
  const float2 fb2 = ((const float2*)fb)[i0];
  const float c8a = 8.f * softplusf_(fb2.x);
  const float c8b = 8.f * softplusf_(fb2.y);
  float apa = 1.f, sa = 0.f, apb = 1.f, sb = 0.f;
  size_t r = (size_t)n * T_S + (size_t)ch * LCH;
  for (int i = 0; i < LCH; i++, r++) {
    unsigned pf = fg2[r * (G2 / 2) + i0];
    unsigned pi = fg2[r * (G2 / 2) + H_M / 2 + i0];
    unsigned px = xbc2[r * (H_M / 2) + i0];
    float alpha_a = __expf(-c8a * sigmoidf_(bf_lo(pf)));
    float alpha_b = __expf(-c8b * sigmoidf_(bf_hi(pf)));
    float beta_a = sqrtf(1.f - alpha_a * alpha_a + 1e-6f);
    float beta_b = sqrtf(1.f - alpha_b * alpha_b + 1e-6f);
    sa = alpha_a * sa + beta_a * sigmoidf_(bf_lo(pi)) * bf_lo(px);
    sb = alpha_b * sb + beta_b * sigmoidf_(bf_hi(pi)) * bf_hi(px);
    apa *= alpha_a;
    apb *= alpha_b;
  }
  size_t o = ((size_t)n * NCH + ch) * (H_M / 2) + i0;
  cA2[o] = make_float2(apa, apb);
  cS2[o] = make_float2(sa, sb);
}

// phase C: per-block prescan of chunk summaries (L2-hot) computes the carry-in,
// then replay with fused gelu(gate)*h written IN-PLACE over the gate buffer.
__global__ void scan_C(const unsigned int* __restrict__ fg2, const unsigned int* __restrict__ xbc2,
                       const float* __restrict__ fb,
                       const float2* __restrict__ cA2, const float2* __restrict__ cS2,
                       unsigned int* gateh2) {
  int i0 = blockIdx.x * 256 + threadIdx.x;
  int ch = blockIdx.y;
  int n = blockIdx.z;
  const float2 fb2 = ((const float2*)fb)[i0];
  const float c8a = 8.f * softplusf_(fb2.x);
  const float c8b = 8.f * softplusf_(fb2.y);
  float sa = 0.f, sb = 0.f;
  for (int c = 0; c < ch; c++) {
    size_t o = ((size_t)n * NCH + c) * (H_M / 2) + i0;
    float2 a = cA2[o], s = cS2[o];
    sa = a.x * sa + s.x;
    sb = a.y * sb + s.y;
  }
  size_t r = (size_t)n * T_S + (size_t)ch * LCH;
  for (int i = 0; i < LCH; i++, r++) {
    unsigned pf = fg2[r * (G2 / 2) + i0];
    unsigned pi = fg2[r * (G2 / 2) + H_M / 2 + i0];
    unsigned px = xbc2[r * (H_M / 2) + i0];
    float alpha_a = __expf(-c8a * sigmoidf_(bf_lo(pf)));
    float alpha_b = __expf(-c8b * sigmoidf_(bf_hi(pf)));
    float beta_a = sqrtf(1.f - alpha_a * alpha_a + 1e-6f);
    float beta_b = sqrtf(1.f - alpha_b * alpha_b + 1e-6f);
    sa = alpha_a * sa + beta_a * sigmoidf_(bf_lo(pi)) * bf_lo(px);
    sb = alpha_b * sb + beta_b * sigmoidf_(bf_hi(pi)) * bf_hi(px);
    unsigned pg = gateh2[r * (H_M / 2) + i0];
    gateh2[r * (H_M / 2) + i0] = bf_pack(geluf_(bf_lo(pg)) * sa, geluf_(bf_hi(pg)) * sb);
  }
}

// ---------------- launcher ----------------
// Workspace layout (S = NT*H_M*2 = 50,331,648 B; peak = 4S + 9.4 MB ≈ 210.8 MB):
//   [0,S)    gate16 (GEMM1 out, lo half) -> scan_C in-place -> gh16 (GEMM3 A)
//   [S,2S)   xbpre16 (GEMM1 out, hi half; conv in; dead after conv)
//   [S,3S)   fg16 (GEMM2 out, overwrites xbpre16 + x16/Win16)
//   [2S,..)  x16 (33.6MB) + Win16 (6.3MB), live only during GEMM1
//   [3S,4S)  xbc16 (conv out; dead after scan_C)
//   [4S,..)  Wg16 (9.4MB, dead after GEMM2) aliased by cA(1.5) + cS(1.5) + Wout16(3.1)
extern "C" void kernel_launch(void* const* d_in, const int* in_sizes, int n_in,
                              void* d_out, int out_size, void* d_ws, size_t ws_size,
                              hipStream_t stream) {
  const float* x    = (const float*)d_in[0];
  const float* Win  = (const float*)d_in[1];
  const float* cw   = (const float*)d_in[2];
  const float* cb   = (const float*)d_in[3];
  const float* Wg   = (const float*)d_in[4];
  const float* bg   = (const float*)d_in[5];
  const float* fb   = (const float*)d_in[6];
  const float* Wout = (const float*)d_in[7];
  float* out = (float*)d_out;
  (void)in_sizes; (void)n_in;

  const size_t S = (size_t)NT * H_M * 2;
  const size_t needed = 4 * S + (size_t)G2 * H_M * 2;
  if (ws_size < needed) {
    zero_out<<<(out_size + 255) / 256, 256, 0, stream>>>(out, out_size);
    return;
  }

  char* base = (char*)d_ws;
  unsigned short* gate16  = (unsigned short*)(base);            // becomes gh16 in-place
  unsigned short* xbpre16 = (unsigned short*)(base + S);
  unsigned short* fg16    = (unsigned short*)(base + S);        // [S,3S) after conv
  unsigned short* x16     = (unsigned short*)(base + 2 * S);    // live during GEMM1 only
  unsigned short* Win16   = (unsigned short*)(base + 2 * S + (size_t)NT * D_M * 2);
  unsigned short* xbc16   = (unsigned short*)(base + 3 * S);
  unsigned short* Wg16    = (unsigned short*)(base + 4 * S);    // dead after GEMM2
  float* cA    = (float*)(base + 4 * S);                        // aliases Wg16 (after GEMM2)
  float* cS    = cA + (size_t)N_B * NCH * H_M;
  unsigned short* Wout16  = (unsigned short*)(cS + (size_t)N_B * NCH * H_M);

  // fused bf16 conversions (x, Win, Wg)
  cvt3_bf16<<<(N4_X + N4_WIN + N4_WG + 255) / 256, 256, 0, stream>>>(
      x, x16, Win, Win16, Wg, Wg16);

  // 1) gx = x @ W_in^T, single dispatch, split output: gate16 | xbpre16
  gemm_bt8<false, true, true><<<dim3(G2 / TN, NT / TM), 512, 0, stream>>>(
      x16, Win16, gate16, xbpre16, nullptr, G2, D_M);
  // 2) depthwise causal conv -> xbc16 (2 ch/thread)
  conv_dw<<<dim3(H_M / 512, T_S, N_B), 256, 0, stream>>>(
      (const unsigned int*)xbpre16, cw, cb, (unsigned int*)xbc16);
  // 3) fg = xbc @ W_g^T + b_g  (overwrites xbpre16/x16/Win16 region)
  gemm_bt8<true, true, false><<<dim3(G2 / TN, NT / TM), 512, 0, stream>>>(
      xbc16, Wg16, fg16, nullptr, bg, G2, H_M);
  // Wout cvt into the now-dead Wg16 slot (after cA/cS)
  cvt_bf16<<<(D_M * H_M / 4 + 255) / 256, 256, 0, stream>>>(Wout, Wout16, D_M * H_M / 4);
  // 4) chunked linear scan + fused gelu(gate)*h (in-place over gate16), 2 ch/thread
  scan_A<<<dim3(H_M / 512, NCH, N_B), 256, 0, stream>>>(
      (const unsigned int*)fg16, (const unsigned int*)xbc16, fb, (float2*)cA, (float2*)cS);
  scan_C<<<dim3(H_M / 512, NCH, N_B), 256, 0, stream>>>(
      (const unsigned int*)fg16, (const unsigned int*)xbc16, fb,
      (const float2*)cA, (const float2*)cS, (unsigned int*)gate16);
  // 5) out = gh @ W_out^T  (fp32 out)
  gemm_bt8<false, false, false><<<dim3(D_M / TN, NT / TM), 512, 0, stream>>>(
      gate16, Wout16, out, nullptr, nullptr, D_M, H_M);
}

// Round 8
// 680.770 us; speedup vs baseline: 1.4763x; 1.4763x over previous
//
#include <hip/hip_runtime.h>
#include <stdint.h>
#include <math.h>

#define N_B 4
#define T_S 4096
#define D_M 1024
#define H_M 1536
#define NT  (N_B * T_S)   // 16384
#define G2  (2 * H_M)     // 3072
#define LCH 64            // timesteps per chunk
#define NCH 64            // chunks (LCH*NCH == T_S)

typedef __attribute__((ext_vector_type(8))) short short8;
typedef __attribute__((ext_vector_type(4))) float floatx4;

__device__ __forceinline__ unsigned short f2bf(float f) {
  unsigned u = __float_as_uint(f);
  u += 0x7fff + ((u >> 16) & 1);            // RNE
  return (unsigned short)(u >> 16);
}
__device__ __forceinline__ float bf2f(unsigned short u) {
  return __uint_as_float(((unsigned)u) << 16);
}
__device__ __forceinline__ float bf_lo(unsigned p) { return __uint_as_float(p << 16); }
__device__ __forceinline__ float bf_hi(unsigned p) { return __uint_as_float(p & 0xffff0000u); }
__device__ __forceinline__ unsigned bf_pack(float lo, float hi) {
  return ((unsigned)f2bf(lo)) | (((unsigned)f2bf(hi)) << 16);
}
__device__ __forceinline__ float sigmoidf_(float x) { return 1.f / (1.f + __expf(-x)); }
__device__ __forceinline__ float softplusf_(float x) {
  return (x > 20.f) ? x : log1pf(__expf(x));
}
__device__ __forceinline__ float geluf_(float x) {
  return 0.5f * x * (1.f + erff(x * 0.70710678118654752f));
}

// ---------------- zero-fill fallback (diagnostic if ws_size too small) ----------------
__global__ void zero_out(float* __restrict__ out, int n) {
  int i = blockIdx.x * 256 + threadIdx.x;
  if (i < n) out[i] = 0.f;
}

// ---------------- fused f32 -> bf16 conversion of x, Win, Wg (one launch) ----------------
#define N4_X   (NT * D_M / 4)          // 4,194,304
#define N4_WIN (G2 * D_M / 4)          //   786,432
#define N4_WG  (G2 * H_M / 4)          // 1,179,648
__global__ void cvt3_bf16(const float* __restrict__ x, unsigned short* __restrict__ x16,
                          const float* __restrict__ win, unsigned short* __restrict__ win16,
                          const float* __restrict__ wg, unsigned short* __restrict__ wg16) {
  int i = blockIdx.x * 256 + threadIdx.x;
  const float* in; unsigned short* out;
  if (i < N4_X)                { in = x;   out = x16; }
  else if (i < N4_X + N4_WIN)  { in = win; out = win16; i -= N4_X; }
  else if (i < N4_X + N4_WIN + N4_WG) { in = wg; out = wg16; i -= N4_X + N4_WIN; }
  else return;
  float4 v = ((const float4*)in)[i];
  ushort4 o;
  o.x = f2bf(v.x); o.y = f2bf(v.y); o.z = f2bf(v.z); o.w = f2bf(v.w);
  ((ushort4*)out)[i] = o;
}

__global__ void cvt_bf16(const float* __restrict__ in, unsigned short* __restrict__ out, int n4) {
  int i = blockIdx.x * 256 + threadIdx.x;
  if (i >= n4) return;
  float4 v = ((const float4*)in)[i];
  ushort4 o;
  o.x = f2bf(v.x); o.y = f2bf(v.y); o.z = f2bf(v.z); o.w = f2bf(v.w);
  ((ushort4*)out)[i] = o;
}

// ---------------- bf16 MFMA GEMM, 256x256 tile, m201-faithful 4-phase cadence ---------
// C[m,n] = sum_k A[m,k]*B[n,k] (+bias[n]).  512 threads = 8 waves (2 Mx4 N), BK=64.
// r7 post-mortem: r6's A-from-global refuted (16 scattered 64B segments per load instr ->
// VMEM-issue-bound, MfmaUtil 18.5%). A must stage via global_load_lds. r2/r3/r4 all land
// 148-152us (44-47%) while m201 (same tile/waves/BK/LDS-traffic/occupancy) measures 62%.
// The un-replicated difference is m201's exact phase cadence -> this kernel ports it
// verbatim onto r2's HW-verified layout (slots, swizzle, staging math, epilogue):
//   per phase: { ds_reads for THIS phase ; stage 1 half-tile of t+1 ; [vmcnt] ;
//                s_barrier ; s_waitcnt lgkmcnt(0) ; setprio(1) ; 16 MFMA ; setprio(0) ;
//                s_barrier }
// Reads issue BEFORE the phase's first barrier (latency drains under barrier skew +
// prior phase's MFMA tail); lgkmcnt(0) after it; 2 barriers/phase (8/tile, m201 cadence).
// Phases (kh, m-half): P1 kh0 af[0..3]+bfr[4] (8 ds_read), P2 kh0 af[4..7] (4, bfr held),
// P3 kh1 af[0..3]+bfr (8), P4 kh1 af[4..7] (4)  -> 24 b128/wave/tile (= r2).
// LDS 128 KiB: lds[2 buf][4 slots: A.kh0,A.kh1,B.kh0,B.kh1][256 rows x 32 k].
// Stage order per tile t (buf q=par^1): A.kh0' @P1, B.kh0' @P2, A.kh1' @P3, B.kh1' @P4.
// Ledger (2 loads/stage): vmcnt(4) @P2 (lands A.kh1,B.kh1 of t, read at P3),
// vmcnt(4) @P4 (lands A.kh0',B.kh0', read at t+1 P1); vmcnt(0) only at last tile's P2.
// Every slot restaged >=2 phases + barrier after its last reader (A.kh0: last read P2,
// restaged t+1 P1 [next buf period]; B.kh0: P1/P2-held -> t+1 P2; A.kh1: P4 -> t+1 P3;
// B.kh1: P3-held-P4 -> t+1 P4). All waits wave-uniform; barriers unconditional.
// Bank swizzle (r2-proven 0 conflicts): read phys k-group = kq ^ ((fr>>1)&3); staging
// global source pre-swizzled g=(tid&3)^((tid>>3)&3), LDS dest linear (rule #21).
// XCD swizzle (r1-proven: FETCH 234->141 MB): bijective, nwg%8==0 for all shapes.
#define TM 256
#define TN 256

__device__ __forceinline__ void stage16(const unsigned short* g, unsigned short* l) {
  __builtin_amdgcn_global_load_lds((__attribute__((address_space(1))) void*)g,
                                   (__attribute__((address_space(3))) void*)l, 16, 0, 0);
}

template<bool BIAS, bool OUT_BF16, bool SPLIT>
__global__ __launch_bounds__(512, 2)
void gemm_bt8(const unsigned short* __restrict__ A,
              const unsigned short* __restrict__ B,
              void* __restrict__ Cv, void* __restrict__ Cv2,
              const float* __restrict__ bias,
              int N, int K) {
  __shared__ __align__(16) unsigned short lds[2][4][8192];   // 128 KiB
  const int tid  = threadIdx.x;
  const int lane = tid & 63;
  const int wave = tid >> 6;
  const int wr = wave >> 2;                  // 0..1  (M half of tile)
  const int wc = wave & 3;                   // 0..3  (N quarter of tile)

  // bijective XCD-aware block swizzle (nwg % 8 == 0 for all shapes used)
  const int gx  = gridDim.x;
  const int nwg = gx * gridDim.y;
  const int bid = blockIdx.y * gx + blockIdx.x;
  const int cpx = nwg >> 3;
  const int swz = (bid & 7) * cpx + (bid >> 3);
  const int bm = (swz / gx) * TM;
  const int bn = (swz % gx) * TN;

  floatx4 acc[8][4];
#pragma unroll
  for (int i = 0; i < 8; i++)
#pragma unroll
    for (int j = 0; j < 4; j++)
      acc[i][j] = (floatx4){0.f, 0.f, 0.f, 0.f};

  // ---- staging (r2 verbatim): one k-half slot = 256 rows x 32 k = 1024 x 16B chunks;
  // thread does c=tid, tid+512. chunk c -> row r=c>>2, phys 16B-slot sl=c&3; fetches
  // global k-group g = sl ^ ((r>>1)&3) = (tid&3)^((tid>>3)&3)  (u-invariant).
  const int r0_ = tid >> 2;                  // 0..127
  const int g8  = ((tid & 3) ^ ((tid >> 3) & 3)) * 8;
  const unsigned short* Ag1 = A + (size_t)(bm + r0_)       * K + g8;
  const unsigned short* Ag2 = A + (size_t)(bm + r0_ + 128) * K + g8;
  const unsigned short* Bg1 = B + (size_t)(bn + r0_)       * K + g8;
  const unsigned short* Bg2 = B + (size_t)(bn + r0_ + 128) * K + g8;
  const int ld1 = tid * 8;                   // elem offset in slot
  const int ld2 = ld1 + 4096;

#define STAGE_A(bu, kh, kb) do { \
    stage16(Ag1 + (kb) + (kh) * 32, &lds[bu][kh][ld1]); \
    stage16(Ag2 + (kb) + (kh) * 32, &lds[bu][kh][ld2]); } while (0)
#define STAGE_B(bu, kh, kb) do { \
    stage16(Bg1 + (kb) + (kh) * 32, &lds[bu][2 + (kh)][ld1]); \
    stage16(Bg2 + (kb) + (kh) * 32, &lds[bu][2 + (kh)][ld2]); } while (0)

  // ---- fragment reads: lane (fr, kq); phys 16B-group = kq ^ ((fr>>1)&3)
  const int fr = lane & 15;
  const int kq = lane >> 4;
  const int sx = (kq ^ ((fr >> 1) & 3)) * 8;
  const int abase = (wr * 128 + fr) * 32 + sx;   // + i*16 rows = i*512 elems
  const int bbase = (wc * 64 + fr) * 32 + sx;    // + j*512

#define MFMA_Q(base) do { \
    __builtin_amdgcn_s_setprio(1); \
    _Pragma("unroll") \
    for (int i = 0; i < 4; ++i) \
      _Pragma("unroll") \
      for (int j = 0; j < 4; ++j) \
        acc[(base) + i][j] = __builtin_amdgcn_mfma_f32_16x16x32_bf16( \
            af[i], bfr[j], acc[(base) + i][j], 0, 0, 0); \
    __builtin_amdgcn_s_setprio(0); } while (0)

  const int nt = K >> 6;
  short8 af[4], bfr[4];

  // prologue: tile 0 -> buf 0, issue order A.kh0, B.kh0, A.kh1, B.kh1
  STAGE_A(0, 0, 0); STAGE_B(0, 0, 0); STAGE_A(0, 1, 0); STAGE_B(0, 1, 0);
  asm volatile("s_waitcnt vmcnt(4)" ::: "memory");   // A.kh0, B.kh0 landed
  __builtin_amdgcn_s_barrier();

  for (int t = 0; t < nt; ++t) {
    const int p  = t & 1;
    const int q  = p ^ 1;
    const int kn = (t + 1) << 6;
    const bool s1 = (t + 1 < nt);

    // ---- P1 (kh0, m0-3): reads first, stage A.kh0(t+1) ----
#pragma unroll
    for (int j = 0; j < 4; ++j) bfr[j] = *(const short8*)(&lds[p][2][bbase + j * 512]);
#pragma unroll
    for (int i = 0; i < 4; ++i) af[i]  = *(const short8*)(&lds[p][0][abase + i * 512]);
    if (s1) STAGE_A(q, 0, kn);
    __builtin_amdgcn_s_barrier();
    asm volatile("s_waitcnt lgkmcnt(0)" ::: "memory");
    MFMA_Q(0);
    __builtin_amdgcn_s_barrier();

    // ---- P2 (kh0, m4-7): bfr held; stage B.kh0(t+1); vmcnt covers kh1(t) ----
#pragma unroll
    for (int i = 0; i < 4; ++i) af[i] = *(const short8*)(&lds[p][0][abase + (4 + i) * 512]);
    if (s1) STAGE_B(q, 0, kn);
    if (s1) { asm volatile("s_waitcnt vmcnt(4)" ::: "memory"); }  // A.kh1(t), B.kh1(t)
    else    { asm volatile("s_waitcnt vmcnt(0)" ::: "memory"); }
    __builtin_amdgcn_s_barrier();
    asm volatile("s_waitcnt lgkmcnt(0)" ::: "memory");
    MFMA_Q(4);
    __builtin_amdgcn_s_barrier();

    // ---- P3 (kh1, m0-3): reads; stage A.kh1(t+1) ----
#pragma unroll
    for (int j = 0; j < 4; ++j) bfr[j] = *(const short8*)(&lds[p][3][bbase + j * 512]);
#pragma unroll
    for (int i = 0; i < 4; ++i) af[i]  = *(const short8*)(&lds[p][1][abase + i * 512]);
    if (s1) STAGE_A(q, 1, kn);
    __builtin_amdgcn_s_barrier();
    asm volatile("s_waitcnt lgkmcnt(0)" ::: "memory");
    MFMA_Q(0);
    __builtin_amdgcn_s_barrier();

    // ---- P4 (kh1, m4-7): bfr held; stage B.kh1(t+1); vmcnt covers kh0(t+1) ----
#pragma unroll
    for (int i = 0; i < 4; ++i) af[i] = *(const short8*)(&lds[p][1][abase + (4 + i) * 512]);
    if (s1) {
      STAGE_B(q, 1, kn);
      asm volatile("s_waitcnt vmcnt(4)" ::: "memory");  // A.kh0(t+1), B.kh0(t+1)
    }
    __builtin_amdgcn_s_barrier();
    asm volatile("s_waitcnt lgkmcnt(0)" ::: "memory");
    MFMA_Q(4);
    __builtin_amdgcn_s_barrier();
  }
#undef STAGE_A
#undef STAGE_B
#undef MFMA_Q

  // C/D layout (m89-verified): col = lane&15, row = (lane>>4)*4 + reg
  // acc[i][j] rows = bm + wr*128 + i*16. stores row-major (j innermost): 64B C-line
  // halves issued back-to-back (r2-proven, WRITE_SIZE == output size).
  const int half  = SPLIT ? (N >> 1) : N;
  const bool hi   = SPLIT && (bn >= half);
  void* Cb        = hi ? Cv2 : Cv;
  const int coff  = hi ? half : 0;
  const int cn = lane & 15;
  const int rb = (lane >> 4) * 4;
  float bv[4];
#pragma unroll
  for (int j = 0; j < 4; ++j)
    bv[j] = BIAS ? bias[bn + wc * 64 + j * 16 + cn] : 0.f;
  const int col0 = bn + wc * 64 + cn - coff;
#pragma unroll
  for (int i = 0; i < 8; ++i) {
    const int row0 = bm + wr * 128 + i * 16 + rb;
#pragma unroll
    for (int r = 0; r < 4; ++r) {
      const size_t rowb = (size_t)(row0 + r) * half + col0;
#pragma unroll
      for (int j = 0; j < 4; ++j) {
        float v = acc[i][j][r] + bv[j];
        if (OUT_BF16) ((unsigned short*)Cb)[rowb + j * 16] = f2bf(v);
        else          ((float*)Cb)[rowb + j * 16] = v;
      }
    }
  }
}

// ---------------- depthwise causal conv (K=4) + bias, 2 channels/thread ----------------
__global__ void conv_dw(const unsigned int* __restrict__ xbpre2, const float* __restrict__ cw,
                        const float* __restrict__ cb, unsigned int* __restrict__ xbc2) {
  int i0 = blockIdx.x * 256 + threadIdx.x;       // pair index, 0..H_M/2-1
  int t = blockIdx.y;
  size_t nt = (size_t)blockIdx.z * T_S + t;
  const int h = 2 * i0;
  const float4 wa = ((const float4*)cw)[h];      // taps for channel h
  const float4 wb = ((const float4*)cw)[h + 1];  // taps for channel h+1
  const float2 cb2 = ((const float2*)cb)[i0];
  size_t base = nt * (H_M / 2) + i0;
  unsigned p0 = xbpre2[base];
  float aa = cb2.x + wa.w * bf_lo(p0);
  float ab = cb2.y + wb.w * bf_hi(p0);
  if (t >= 1) { unsigned p = xbpre2[base - H_M / 2];
    aa += wa.z * bf_lo(p); ab += wb.z * bf_hi(p); }
  if (t >= 2) { unsigned p = xbpre2[base - 2 * (size_t)(H_M / 2)];
    aa += wa.y * bf_lo(p); ab += wb.y * bf_hi(p); }
  if (t >= 3) { unsigned p = xbpre2[base - 3 * (size_t)(H_M / 2)];
    aa += wa.x * bf_lo(p); ab += wb.x * bf_hi(p); }
  xbc2[base] = bf_pack(aa, ab);
}

// ---------------- chunked linear scan (2 channels/thread) ----------------
__global__ void scan_A(const unsigned int* __restrict__ fg2, const unsigned int* __restrict__ xbc2,
                       const float* __restrict__ fb,
                       float2* __restrict__ cA2, float2* __restrict__ cS2) {
  int i0 = blockIdx.x * 256 + threadIdx.x;       // pair index
  int ch = blockIdx.y;
  int n = blockIdx.z;
  const float2 fb2 = ((const float2*)fb)[i0];
  const float c8a = 8.f * softplusf_(fb2.x);
  const float c8b = 8.f * softplusf_(fb2.y);
  float apa = 1.f, sa = 0.f, apb = 1.f, sb = 0.f;
  size_t r = (size_t)n * T_S + (size_t)ch * LCH;
  for (int i = 0; i < LCH; i++, r++) {
    unsigned pf = fg2[r * (G2 / 2) + i0];
    unsigned pi = fg2[r * (G2 / 2) + H_M / 2 + i0];
    unsigned px = xbc2[r * (H_M / 2) + i0];
    float alpha_a = __expf(-c8a * sigmoidf_(bf_lo(pf)));
    float alpha_b = __expf(-c8b * sigmoidf_(bf_hi(pf)));
    float beta_a = sqrtf(1.f - alpha_a * alpha_a + 1e-6f);
    float beta_b = sqrtf(1.f - alpha_b * alpha_b + 1e-6f);
    sa = alpha_a * sa + beta_a * sigmoidf_(bf_lo(pi)) * bf_lo(px);
    sb = alpha_b * sb + beta_b * sigmoidf_(bf_hi(pi)) * bf_hi(px);
    apa *= alpha_a;
    apb *= alpha_b;
  }
  size_t o = ((size_t)n * NCH + ch) * (H_M / 2) + i0;
  cA2[o] = make_float2(apa, apb);
  cS2[o] = make_float2(sa, sb);
}

// phase C: per-block prescan of chunk summaries (L2-hot) computes the carry-in,
// then replay with fused gelu(gate)*h written IN-PLACE over the gate buffer.
__global__ void scan_C(const unsigned int* __restrict__ fg2, const unsigned int* __restrict__ xbc2,
                       const float* __restrict__ fb,
                       const float2* __restrict__ cA2, const float2* __restrict__ cS2,
                       unsigned int* gateh2) {
  int i0 = blockIdx.x * 256 + threadIdx.x;
  int ch = blockIdx.y;
  int n = blockIdx.z;
  const float2 fb2 = ((const float2*)fb)[i0];
  const float c8a = 8.f * softplusf_(fb2.x);
  const float c8b = 8.f * softplusf_(fb2.y);
  float sa = 0.f, sb = 0.f;
  for (int c = 0; c < ch; c++) {
    size_t o = ((size_t)n * NCH + c) * (H_M / 2) + i0;
    float2 a = cA2[o], s = cS2[o];
    sa = a.x * sa + s.x;
    sb = a.y * sb + s.y;
  }
  size_t r = (size_t)n * T_S + (size_t)ch * LCH;
  for (int i = 0; i < LCH; i++, r++) {
    unsigned pf = fg2[r * (G2 / 2) + i0];
    unsigned pi = fg2[r * (G2 / 2) + H_M / 2 + i0];
    unsigned px = xbc2[r * (H_M / 2) + i0];
    float alpha_a = __expf(-c8a * sigmoidf_(bf_lo(pf)));
    float alpha_b = __expf(-c8b * sigmoidf_(bf_hi(pf)));
    float beta_a = sqrtf(1.f - alpha_a * alpha_a + 1e-6f);
    float beta_b = sqrtf(1.f - alpha_b * alpha_b + 1e-6f);
    sa = alpha_a * sa + beta_a * sigmoidf_(bf_lo(pi)) * bf_lo(px);
    sb = alpha_b * sb + beta_b * sigmoidf_(bf_hi(pi)) * bf_hi(px);
    unsigned pg = gateh2[r * (H_M / 2) + i0];
    gateh2[r * (H_M / 2) + i0] = bf_pack(geluf_(bf_lo(pg)) * sa, geluf_(bf_hi(pg)) * sb);
  }
}

// ---------------- launcher ----------------
// Workspace layout (S = NT*H_M*2 = 50,331,648 B; peak = 4S + 9.4 MB ≈ 210.8 MB):
//   [0,S)    gate16 (GEMM1 out, lo half) -> scan_C in-place -> gh16 (GEMM3 A)
//   [S,2S)   xbpre16 (GEMM1 out, hi half; conv in; dead after conv)
//   [S,3S)   fg16 (GEMM2 out, overwrites xbpre16 + x16/Win16)
//   [2S,..)  x16 (33.6MB) + Win16 (6.3MB), live only during GEMM1
//   [3S,4S)  xbc16 (conv out; dead after scan_C)
//   [4S,..)  Wg16 (9.4MB, dead after GEMM2) aliased by cA(1.5) + cS(1.5) + Wout16(3.1)
extern "C" void kernel_launch(void* const* d_in, const int* in_sizes, int n_in,
                              void* d_out, int out_size, void* d_ws, size_t ws_size,
                              hipStream_t stream) {
  const float* x    = (const float*)d_in[0];
  const float* Win  = (const float*)d_in[1];
  const float* cw   = (const float*)d_in[2];
  const float* cb   = (const float*)d_in[3];
  const float* Wg   = (const float*)d_in[4];
  const float* bg   = (const float*)d_in[5];
  const float* fb   = (const float*)d_in[6];
  const float* Wout = (const float*)d_in[7];
  float* out = (float*)d_out;
  (void)in_sizes; (void)n_in;

  const size_t S = (size_t)NT * H_M * 2;
  const size_t needed = 4 * S + (size_t)G2 * H_M * 2;
  if (ws_size < needed) {
    zero_out<<<(out_size + 255) / 256, 256, 0, stream>>>(out, out_size);
    return;
  }

  char* base = (char*)d_ws;
  unsigned short* gate16  = (unsigned short*)(base);            // becomes gh16 in-place
  unsigned short* xbpre16 = (unsigned short*)(base + S);
  unsigned short* fg16    = (unsigned short*)(base + S);        // [S,3S) after conv
  unsigned short* x16     = (unsigned short*)(base + 2 * S);    // live during GEMM1 only
  unsigned short* Win16   = (unsigned short*)(base + 2 * S + (size_t)NT * D_M * 2);
  unsigned short* xbc16   = (unsigned short*)(base + 3 * S);
  unsigned short* Wg16    = (unsigned short*)(base + 4 * S);    // dead after GEMM2
  float* cA    = (float*)(base + 4 * S);                        // aliases Wg16 (after GEMM2)
  float* cS    = cA + (size_t)N_B * NCH * H_M;
  unsigned short* Wout16  = (unsigned short*)(cS + (size_t)N_B * NCH * H_M);

  // fused bf16 conversions (x, Win, Wg)
  cvt3_bf16<<<(N4_X + N4_WIN + N4_WG + 255) / 256, 256, 0, stream>>>(
      x, x16, Win, Win16, Wg, Wg16);

  // 1) gx = x @ W_in^T, single dispatch, split output: gate16 | xbpre16
  gemm_bt8<false, true, true><<<dim3(G2 / TN, NT / TM), 512, 0, stream>>>(
      x16, Win16, gate16, xbpre16, nullptr, G2, D_M);
  // 2) depthwise causal conv -> xbc16 (2 ch/thread)
  conv_dw<<<dim3(H_M / 512, T_S, N_B), 256, 0, stream>>>(
      (const unsigned int*)xbpre16, cw, cb, (unsigned int*)xbc16);
  // 3) fg = xbc @ W_g^T + b_g  (overwrites xbpre16/x16/Win16 region)
  gemm_bt8<true, true, false><<<dim3(G2 / TN, NT / TM), 512, 0, stream>>>(
      xbc16, Wg16, fg16, nullptr, bg, G2, H_M);
  // Wout cvt into the now-dead Wg16 slot (after cA/cS)
  cvt_bf16<<<(D_M * H_M / 4 + 255) / 256, 256, 0, stream>>>(Wout, Wout16, D_M * H_M / 4);
  // 4) chunked linear scan + fused gelu(gate)*h (in-place over gate16), 2 ch/thread
  scan_A<<<dim3(H_M / 512, NCH, N_B), 256, 0, stream>>>(
      (const unsigned int*)fg16, (const unsigned int*)xbc16, fb, (float2*)cA, (float2*)cS);
  scan_C<<<dim3(H_M / 512, NCH, N_B), 256, 0, stream>>>(
      (const unsigned int*)fg16, (const unsigned int*)xbc16, fb,
      (const float2*)cA, (const float2*)cS, (unsigned int*)gate16);
  // 5) out = gh @ W_out^T  (fp32 out)
  gemm_bt8<false, false, false><<<dim3(D_M / TN, NT / TM), 512, 0, stream>>>(
      gate16, Wout16, out, nullptr, nullptr, D_M, H_M);
}

// Round 9
// 596.737 us; speedup vs baseline: 1.6842x; 1.1408x over previous
//
#include <hip/hip_runtime.h>
#include <stdint.h>
#include <math.h>

#define N_B 4
#define T_S 4096
#define D_M 1024
#define H_M 1536
#define NT  (N_B * T_S)   // 16384
#define G2  (2 * H_M)     // 3072
#define LCH 32            // timesteps per chunk
#define NCH 128           // chunks (LCH*NCH == T_S)

typedef __attribute__((ext_vector_type(8))) short short8;
typedef __attribute__((ext_vector_type(4))) float floatx4;

__device__ __forceinline__ unsigned short f2bf(float f) {
  unsigned u = __float_as_uint(f);
  u += 0x7fff + ((u >> 16) & 1);            // RNE
  return (unsigned short)(u >> 16);
}
__device__ __forceinline__ float bf2f(unsigned short u) {
  return __uint_as_float(((unsigned)u) << 16);
}
__device__ __forceinline__ float bf_lo(unsigned p) { return __uint_as_float(p << 16); }
__device__ __forceinline__ float bf_hi(unsigned p) { return __uint_as_float(p & 0xffff0000u); }
__device__ __forceinline__ unsigned bf_pack(float lo, float hi) {
  return ((unsigned)f2bf(lo)) | (((unsigned)f2bf(hi)) << 16);
}
__device__ __forceinline__ float sigmoidf_(float x) { return 1.f / (1.f + __expf(-x)); }
__device__ __forceinline__ float softplusf_(float x) {
  return (x > 20.f) ? x : log1pf(__expf(x));
}
__device__ __forceinline__ float geluf_(float x) {
  return 0.5f * x * (1.f + erff(x * 0.70710678118654752f));
}

// ---------------- zero-fill fallback (diagnostic if ws_size too small) ----------------
__global__ void zero_out(float* __restrict__ out, int n) {
  int i = blockIdx.x * 256 + threadIdx.x;
  if (i < n) out[i] = 0.f;
}

// ---------------- fused f32 -> bf16 conversion of x, Win, Wg (one launch) ----------------
#define N4_X   (NT * D_M / 4)          // 4,194,304
#define N4_WIN (G2 * D_M / 4)          //   786,432
#define N4_WG  (G2 * H_M / 4)          // 1,179,648
__global__ void cvt3_bf16(const float* __restrict__ x, unsigned short* __restrict__ x16,
                          const float* __restrict__ win, unsigned short* __restrict__ win16,
                          const float* __restrict__ wg, unsigned short* __restrict__ wg16) {
  int i = blockIdx.x * 256 + threadIdx.x;
  const float* in; unsigned short* out;
  if (i < N4_X)                { in = x;   out = x16; }
  else if (i < N4_X + N4_WIN)  { in = win; out = win16; i -= N4_X; }
  else if (i < N4_X + N4_WIN + N4_WG) { in = wg; out = wg16; i -= N4_X + N4_WIN; }
  else return;
  float4 v = ((const float4*)in)[i];
  ushort4 o;
  o.x = f2bf(v.x); o.y = f2bf(v.y); o.z = f2bf(v.z); o.w = f2bf(v.w);
  ((ushort4*)out)[i] = o;
}

__global__ void cvt_bf16(const float* __restrict__ in, unsigned short* __restrict__ out, int n4) {
  int i = blockIdx.x * 256 + threadIdx.x;
  if (i >= n4) return;
  float4 v = ((const float4*)in)[i];
  ushort4 o;
  o.x = f2bf(v.x); o.y = f2bf(v.y); o.z = f2bf(v.z); o.w = f2bf(v.w);
  ((ushort4*)out)[i] = o;
}

// ---------------- bf16 MFMA GEMM, 256x256 tile, 4-phase k-half ring schedule ----------
// r2-VERBATIM (session best: GEMM2 149us @ MfmaUtil 46.7, 0 bank conflicts).
// Five schedule variants (r2 ring / r3 top-reads / r4 deep-prefetch / r6 A-global /
// r8 m201-cadence) bracket 148-341us; r2 is the proven optimum of this family -> frozen.
// C[m,n] = sum_k A[m,k]*B[n,k] (+bias[n]).  512 threads = 8 waves (2 Mx4 N), BK=64.
// LDS 64 KiB ring of 4 k-half slots: [A.kh0][A.kh1][B.kh0][B.kh1], each [256 rows x 32 k].
// Phases per tile = (khalf, nhalf), 16 MFMA each; A-frags (8) read once per khalf and
// register-held across both n-phases; B-frags (2) read per phase.
// Slot lifetimes: A.kh0 last read P1, restaged (t+1) at P2; B.kh0 last read P2, restaged P3;
// A.kh1 last read P3, restaged P4; B.kh1 last read P4, restaged next P1. Stage issues always
// come AFTER the post-MFMA barrier of the slot's last reading phase -> no write/read race.
// Counted waits (per-thread ledger, 2 loads per stage unit, 8 outstanding max):
//   P1: issue B.kh1(t); vmcnt(4) -> A.kh0(t),B.kh0(t) landed (issued 3 phases earlier)
//   P3: issue B.kh0(t+1); vmcnt(4) -> A.kh1(t),B.kh1(t) landed (2-3 phases earlier)
// Never drains in main loop; vmcnt(0) only at final tile's P3. Raw s_barrier (6/tile),
// s_setprio(1) around MFMA clusters (T5).
// Bank swizzle (0 conflicts measured): phys slot = kq ^ ((fr>>1)&3) on reads; global
// source pre-swizzled g=(tid&3)^((tid>>3)&3) with linear LDS dest (rule #21).
// XCD swizzle (r1-proven: FETCH 234->141 MB): bijective, nwg%8==0 for all shapes.
#define TM 256
#define TN 256

__device__ __forceinline__ void stage16(const unsigned short* g, unsigned short* l) {
  __builtin_amdgcn_global_load_lds((__attribute__((address_space(1))) void*)g,
                                   (__attribute__((address_space(3))) void*)l, 16, 0, 0);
}

template<bool BIAS, bool OUT_BF16, bool SPLIT>
__global__ __launch_bounds__(512, 2)
void gemm_bt8(const unsigned short* __restrict__ A,
              const unsigned short* __restrict__ B,
              void* __restrict__ Cv, void* __restrict__ Cv2,
              const float* __restrict__ bias,
              int N, int K) {
  // ring slots: 0=A.kh0, 1=A.kh1, 2=B.kh0, 3=B.kh1 ; each 256x32 bf16 = 16 KB
  __shared__ __align__(16) unsigned short lds[4][8192];
  const int tid  = threadIdx.x;
  const int lane = tid & 63;
  const int wave = tid >> 6;
  const int wr = wave >> 2;                  // 0..1  (M half of tile)
  const int wc = wave & 3;                   // 0..3  (N quarter of tile)

  // bijective XCD-aware block swizzle (nwg % 8 == 0 for all shapes used)
  const int gx  = gridDim.x;
  const int nwg = gx * gridDim.y;
  const int bid = blockIdx.y * gx + blockIdx.x;
  const int cpx = nwg >> 3;
  const int swz = (bid & 7) * cpx + (bid >> 3);
  const int bm = (swz / gx) * TM;
  const int bn = (swz % gx) * TN;

  floatx4 acc[8][4];
#pragma unroll
  for (int i = 0; i < 8; i++)
#pragma unroll
    for (int j = 0; j < 4; j++)
      acc[i][j] = (floatx4){0.f, 0.f, 0.f, 0.f};

  // ---- staging: one k-half unit = 256 rows x 32 k = 1024 x 16B chunks; thread does 2.
  // chunk c = tid + 512u -> row r = c>>2 (= tid>>2 + 128u), phys slot sl = c&3.
  // logical k-group fetched: g = sl ^ ((r>>1)&3) = (tid&3) ^ ((tid>>3)&3)  (u-invariant).
  const int r0_ = tid >> 2;                  // 0..127
  const int g8  = ((tid & 3) ^ ((tid >> 3) & 3)) * 8;
  const unsigned short* Ag1 = A + (size_t)(bm + r0_)       * K + g8;
  const unsigned short* Ag2 = A + (size_t)(bm + r0_ + 128) * K + g8;
  const unsigned short* Bg1 = B + (size_t)(bn + r0_)       * K + g8;
  const unsigned short* Bg2 = B + (size_t)(bn + r0_ + 128) * K + g8;
  const int ld1 = tid * 8;                   // elem offset in slot
  const int ld2 = ld1 + 4096;

#define STAGE_A(kh, kb) do { \
    stage16(Ag1 + (kb) + (kh) * 32, &lds[kh][ld1]); \
    stage16(Ag2 + (kb) + (kh) * 32, &lds[kh][ld2]); } while (0)
#define STAGE_B(kh, kb) do { \
    stage16(Bg1 + (kb) + (kh) * 32, &lds[2 + (kh)][ld1]); \
    stage16(Bg2 + (kb) + (kh) * 32, &lds[2 + (kh)][ld2]); } while (0)

  // ---- fragment read bases: lane (fr, kq); phys slot = kq ^ ((fr>>1)&3)
  const int fr = lane & 15;
  const int kq = lane >> 4;
  const int sx = (kq ^ ((fr >> 1) & 3)) * 8;
  const int abase = (wr * 128 + fr) * 32 + sx;   // + i*512
  const int bbase = (wc * 64 + fr) * 32 + sx;    // + j*512

  const int nt = K >> 6;
  short8 af[8], bfr[2];

  // prologue: issue A.kh0(0), B.kh0(0), A.kh1(0) -- matches steady-state ledger order
  STAGE_A(0, 0); STAGE_B(0, 0); STAGE_A(1, 0);

  for (int t = 0; t < nt; ++t) {
    const int k0 = t << 6;
    const int kn = k0 + 64;
    const bool st = (t + 1 < nt);

    // ---- P1: (kh0, n01) ----
    STAGE_B(1, k0);                                  // B.kh1(t) -> slot 3
    asm volatile("s_waitcnt vmcnt(4)" ::: "memory"); // A.kh0(t), B.kh0(t) landed
    __builtin_amdgcn_s_barrier();
#pragma unroll
    for (int i = 0; i < 8; ++i) af[i]  = *(const short8*)(&lds[0][abase + i * 512]);
#pragma unroll
    for (int j = 0; j < 2; ++j) bfr[j] = *(const short8*)(&lds[2][bbase + j * 512]);
    __builtin_amdgcn_s_setprio(1);
#pragma unroll
    for (int i = 0; i < 8; ++i)
#pragma unroll
      for (int j = 0; j < 2; ++j)
        acc[i][j] = __builtin_amdgcn_mfma_f32_16x16x32_bf16(af[i], bfr[j], acc[i][j], 0, 0, 0);
    __builtin_amdgcn_s_setprio(0);
    __builtin_amdgcn_s_barrier();

    // ---- P2: (kh0, n23), A-frags reused ----
    if (st) STAGE_A(0, kn);                          // A.kh0(t+1) -> slot 0
#pragma unroll
    for (int j = 0; j < 2; ++j) bfr[j] = *(const short8*)(&lds[2][bbase + 1024 + j * 512]);
    __builtin_amdgcn_s_setprio(1);
#pragma unroll
    for (int i = 0; i < 8; ++i)
#pragma unroll
      for (int j = 0; j < 2; ++j)
        acc[i][2 + j] = __builtin_amdgcn_mfma_f32_16x16x32_bf16(af[i], bfr[j], acc[i][2 + j], 0, 0, 0);
    __builtin_amdgcn_s_setprio(0);
    __builtin_amdgcn_s_barrier();

    // ---- P3: (kh1, n01) ----
    if (st) STAGE_B(0, kn);                          // B.kh0(t+1) -> slot 2
    if (st) { asm volatile("s_waitcnt vmcnt(4)" ::: "memory"); }  // A.kh1(t), B.kh1(t)
    else    { asm volatile("s_waitcnt vmcnt(0)" ::: "memory"); }
    __builtin_amdgcn_s_barrier();
#pragma unroll
    for (int i = 0; i < 8; ++i) af[i]  = *(const short8*)(&lds[1][abase + i * 512]);
#pragma unroll
    for (int j = 0; j < 2; ++j) bfr[j] = *(const short8*)(&lds[3][bbase + j * 512]);
    __builtin_amdgcn_s_setprio(1);
#pragma unroll
    for (int i = 0; i < 8; ++i)
#pragma unroll
      for (int j = 0; j < 2; ++j)
        acc[i][j] = __builtin_amdgcn_mfma_f32_16x16x32_bf16(af[i], bfr[j], acc[i][j], 0, 0, 0);
    __builtin_amdgcn_s_setprio(0);
    __builtin_amdgcn_s_barrier();

    // ---- P4: (kh1, n23), A-frags reused ----
    if (st) STAGE_A(1, kn);                          // A.kh1(t+1) -> slot 1
#pragma unroll
    for (int j = 0; j < 2; ++j) bfr[j] = *(const short8*)(&lds[3][bbase + 1024 + j * 512]);
    __builtin_amdgcn_s_setprio(1);
#pragma unroll
    for (int i = 0; i < 8; ++i)
#pragma unroll
      for (int j = 0; j < 2; ++j)
        acc[i][2 + j] = __builtin_amdgcn_mfma_f32_16x16x32_bf16(af[i], bfr[j], acc[i][2 + j], 0, 0, 0);
    __builtin_amdgcn_s_setprio(0);
    __builtin_amdgcn_s_barrier();
  }
#undef STAGE_A
#undef STAGE_B

  // C/D layout (m89-verified): col = lane&15, row = (lane>>4)*4 + reg
  // stores row-major (j innermost): 64B C-line halves issued back-to-back (r2-proven,
  // WRITE_SIZE == output size).
  const int half  = SPLIT ? (N >> 1) : N;
  const bool hi   = SPLIT && (bn >= half);
  void* Cb        = hi ? Cv2 : Cv;
  const int coff  = hi ? half : 0;
  const int cn = lane & 15;
  const int rb = (lane >> 4) * 4;
  float bv[4];
#pragma unroll
  for (int j = 0; j < 4; ++j)
    bv[j] = BIAS ? bias[bn + wc * 64 + j * 16 + cn] : 0.f;
  const int col0 = bn + wc * 64 + cn - coff;
#pragma unroll
  for (int i = 0; i < 8; ++i) {
    const int row0 = bm + wr * 128 + i * 16 + rb;
#pragma unroll
    for (int r = 0; r < 4; ++r) {
      const size_t rowb = (size_t)(row0 + r) * half + col0;
#pragma unroll
      for (int j = 0; j < 4; ++j) {
        float v = acc[i][j][r] + bv[j];
        if (OUT_BF16) ((unsigned short*)Cb)[rowb + j * 16] = f2bf(v);
        else          ((float*)Cb)[rowb + j * 16] = v;
      }
    }
  }
}

// ---------------- depthwise causal conv (K=4) + bias, STRIP form ----------------------
// r8 tail rework: old form = 12.6M threads x {4 loads, 1 store, 16 FLOP} (4x read
// amplification, minimal ILP). Strip form: each thread produces 8 consecutive timesteps
// for 2 channels with a rolling 4-tap window: 11 loads / 8 stores, fully unrolled ->
// 11 independent loads in flight, 8x fewer threads. Output bitwise-identical (same
// per-element op order). Wave access: 64 lanes consecutive i0 -> 256B coalesced lines.
#define CT 8   // timesteps per thread
__global__ void conv_dw(const unsigned int* __restrict__ xbpre2, const float* __restrict__ cw,
                        const float* __restrict__ cb, unsigned int* __restrict__ xbc2) {
  int i0 = blockIdx.x * 256 + threadIdx.x;       // pair index, 0..H_M/2-1
  int t0 = blockIdx.y * CT;
  size_t nt = (size_t)blockIdx.z * T_S + t0;
  const int h = 2 * i0;
  const float4 wa = ((const float4*)cw)[h];      // taps for channel h
  const float4 wb = ((const float4*)cw)[h + 1];  // taps for channel h+1
  const float2 cb2 = ((const float2*)cb)[i0];
  size_t base = nt * (H_M / 2) + i0;
  // rolling window (zeros before t=0, causal)
  float xm1a = 0.f, xm1b = 0.f, xm2a = 0.f, xm2b = 0.f, xm3a = 0.f, xm3b = 0.f;
  if (t0 >= 1) { unsigned p = xbpre2[base - (size_t)(H_M / 2)];
    xm1a = bf_lo(p); xm1b = bf_hi(p); }
  if (t0 >= 2) { unsigned p = xbpre2[base - 2 * (size_t)(H_M / 2)];
    xm2a = bf_lo(p); xm2b = bf_hi(p); }
  if (t0 >= 3) { unsigned p = xbpre2[base - 3 * (size_t)(H_M / 2)];
    xm3a = bf_lo(p); xm3b = bf_hi(p); }
#pragma unroll
  for (int s = 0; s < CT; ++s) {
    unsigned p0 = xbpre2[base + (size_t)s * (H_M / 2)];
    float xa = bf_lo(p0), xb = bf_hi(p0);
    float aa = cb2.x + wa.w * xa + wa.z * xm1a + wa.y * xm2a + wa.x * xm3a;
    float ab = cb2.y + wb.w * xb + wb.z * xm1b + wb.y * xm2b + wb.x * xm3b;
    xbc2[base + (size_t)s * (H_M / 2)] = bf_pack(aa, ab);
    xm3a = xm2a; xm2a = xm1a; xm1a = xa;
    xm3b = xm2b; xm2b = xm1b; xm1b = xb;
  }
}

// ---------------- chunked linear scan (2 channels/thread) ----------------
// r8 tail rework: NCH 64->128 (LCH 32) doubles TLP (24 waves/CU) to hide HBM latency;
// unroll 2 keeps 2 iterations of independent loads in flight.
__global__ void scan_A(const unsigned int* __restrict__ fg2, const unsigned int* __restrict__ xbc2,
                       const float* __restrict__ fb,
                       float2* __restrict__ cA2, float2* __restrict__ cS2) {
  int i0 = blockIdx.x * 256 + threadIdx.x;       // pair index
  int ch = blockIdx.y;
  int n = blockIdx.z;
  const float2 fb2 = ((const float2*)fb)[i0];
  const float c8a = 8.f * softplusf_(fb2.x);
  const float c8b = 8.f * softplusf_(fb2.y);
  float apa = 1.f, sa = 0.f, apb = 1.f, sb = 0.f;
  size_t r = (size_t)n * T_S + (size_t)ch * LCH;
#pragma unroll 2
  for (int i = 0; i < LCH; i++, r++) {
    unsigned pf = fg2[r * (G2 / 2) + i0];
    unsigned pi = fg2[r * (G2 / 2) + H_M / 2 + i0];
    unsigned px = xbc2[r * (H_M / 2) + i0];
    float alpha_a = __expf(-c8a * sigmoidf_(bf_lo(pf)));
    float alpha_b = __expf(-c8b * sigmoidf_(bf_hi(pf)));
    float beta_a = sqrtf(1.f - alpha_a * alpha_a + 1e-6f);
    float beta_b = sqrtf(1.f - alpha_b * alpha_b + 1e-6f);
    sa = alpha_a * sa + beta_a * sigmoidf_(bf_lo(pi)) * bf_lo(px);
    sb = alpha_b * sb + beta_b * sigmoidf_(bf_hi(pi)) * bf_hi(px);
    apa *= alpha_a;
    apb *= alpha_b;
  }
  size_t o = ((size_t)n * NCH + ch) * (H_M / 2) + i0;
  cA2[o] = make_float2(apa, apb);
  cS2[o] = make_float2(sa, sb);
}

// phase C: per-block prescan of chunk summaries (L2-hot) computes the carry-in,
// then replay with fused gelu(gate)*h written IN-PLACE over the gate buffer.
__global__ void scan_C(const unsigned int* __restrict__ fg2, const unsigned int* __restrict__ xbc2,
                       const float* __restrict__ fb,
                       const float2* __restrict__ cA2, const float2* __restrict__ cS2,
                       unsigned int* gateh2) {
  int i0 = blockIdx.x * 256 + threadIdx.x;
  int ch = blockIdx.y;
  int n = blockIdx.z;
  const float2 fb2 = ((const float2*)fb)[i0];
  const float c8a = 8.f * softplusf_(fb2.x);
  const float c8b = 8.f * softplusf_(fb2.y);
  float sa = 0.f, sb = 0.f;
  for (int c = 0; c < ch; c++) {
    size_t o = ((size_t)n * NCH + c) * (H_M / 2) + i0;
    float2 a = cA2[o], s = cS2[o];
    sa = a.x * sa + s.x;
    sb = a.y * sb + s.y;
  }
  size_t r = (size_t)n * T_S + (size_t)ch * LCH;
#pragma unroll 2
  for (int i = 0; i < LCH; i++, r++) {
    unsigned pf = fg2[r * (G2 / 2) + i0];
    unsigned pi = fg2[r * (G2 / 2) + H_M / 2 + i0];
    unsigned px = xbc2[r * (H_M / 2) + i0];
    float alpha_a = __expf(-c8a * sigmoidf_(bf_lo(pf)));
    float alpha_b = __expf(-c8b * sigmoidf_(bf_hi(pf)));
    float beta_a = sqrtf(1.f - alpha_a * alpha_a + 1e-6f);
    float beta_b = sqrtf(1.f - alpha_b * alpha_b + 1e-6f);
    sa = alpha_a * sa + beta_a * sigmoidf_(bf_lo(pi)) * bf_lo(px);
    sb = alpha_b * sb + beta_b * sigmoidf_(bf_hi(pi)) * bf_hi(px);
    unsigned pg = gateh2[r * (H_M / 2) + i0];
    gateh2[r * (H_M / 2) + i0] = bf_pack(geluf_(bf_lo(pg)) * sa, geluf_(bf_hi(pg)) * sb);
  }
}

// ---------------- launcher ----------------
// Workspace layout (S = NT*H_M*2 = 50,331,648 B; peak = 4S + 9.4 MB ≈ 210.8 MB):
//   [0,S)    gate16 (GEMM1 out, lo half) -> scan_C in-place -> gh16 (GEMM3 A)
//   [S,2S)   xbpre16 (GEMM1 out, hi half; conv in; dead after conv)
//   [S,3S)   fg16 (GEMM2 out, overwrites xbpre16 + x16/Win16)
//   [2S,..)  x16 (33.6MB) + Win16 (6.3MB), live only during GEMM1
//   [3S,4S)  xbc16 (conv out; dead after scan_C)
//   [4S,..)  Wg16 (9.4MB, dead after GEMM2) aliased by cA(3.1) + cS(3.1) + Wout16(3.1)
//            (NCH=128: 6.29+3.15 MB fits the 9.44 MB region exactly)
extern "C" void kernel_launch(void* const* d_in, const int* in_sizes, int n_in,
                              void* d_out, int out_size, void* d_ws, size_t ws_size,
                              hipStream_t stream) {
  const float* x    = (const float*)d_in[0];
  const float* Win  = (const float*)d_in[1];
  const float* cw   = (const float*)d_in[2];
  const float* cb   = (const float*)d_in[3];
  const float* Wg   = (const float*)d_in[4];
  const float* bg   = (const float*)d_in[5];
  const float* fb   = (const float*)d_in[6];
  const float* Wout = (const float*)d_in[7];
  float* out = (float*)d_out;
  (void)in_sizes; (void)n_in;

  const size_t S = (size_t)NT * H_M * 2;
  const size_t needed = 4 * S + (size_t)G2 * H_M * 2;
  if (ws_size < needed) {
    zero_out<<<(out_size + 255) / 256, 256, 0, stream>>>(out, out_size);
    return;
  }

  char* base = (char*)d_ws;
  unsigned short* gate16  = (unsigned short*)(base);            // becomes gh16 in-place
  unsigned short* xbpre16 = (unsigned short*)(base + S);
  unsigned short* fg16    = (unsigned short*)(base + S);        // [S,3S) after conv
  unsigned short* x16     = (unsigned short*)(base + 2 * S);    // live during GEMM1 only
  unsigned short* Win16   = (unsigned short*)(base + 2 * S + (size_t)NT * D_M * 2);
  unsigned short* xbc16   = (unsigned short*)(base + 3 * S);
  unsigned short* Wg16    = (unsigned short*)(base + 4 * S);    // dead after GEMM2
  float* cA    = (float*)(base + 4 * S);                        // aliases Wg16 (after GEMM2)
  float* cS    = cA + (size_t)N_B * NCH * H_M;
  unsigned short* Wout16  = (unsigned short*)(cS + (size_t)N_B * NCH * H_M);

  // fused bf16 conversions (x, Win, Wg)
  cvt3_bf16<<<(N4_X + N4_WIN + N4_WG + 255) / 256, 256, 0, stream>>>(
      x, x16, Win, Win16, Wg, Wg16);

  // 1) gx = x @ W_in^T, single dispatch, split output: gate16 | xbpre16
  gemm_bt8<false, true, true><<<dim3(G2 / TN, NT / TM), 512, 0, stream>>>(
      x16, Win16, gate16, xbpre16, nullptr, G2, D_M);
  // 2) depthwise causal conv -> xbc16 (strip form, 8 t/thread)
  conv_dw<<<dim3(H_M / 512, T_S / CT, N_B), 256, 0, stream>>>(
      (const unsigned int*)xbpre16, cw, cb, (unsigned int*)xbc16);
  // 3) fg = xbc @ W_g^T + b_g  (overwrites xbpre16/x16/Win16 region)
  gemm_bt8<true, true, false><<<dim3(G2 / TN, NT / TM), 512, 0, stream>>>(
      xbc16, Wg16, fg16, nullptr, bg, G2, H_M);
  // Wout cvt into the now-dead Wg16 slot (after cA/cS)
  cvt_bf16<<<(D_M * H_M / 4 + 255) / 256, 256, 0, stream>>>(Wout, Wout16, D_M * H_M / 4);
  // 4) chunked linear scan + fused gelu(gate)*h (in-place over gate16), 2 ch/thread
  scan_A<<<dim3(H_M / 512, NCH, N_B), 256, 0, stream>>>(
      (const unsigned int*)fg16, (const unsigned int*)xbc16, fb, (float2*)cA, (float2*)cS);
  scan_C<<<dim3(H_M / 512, NCH, N_B), 256, 0, stream>>>(
      (const unsigned int*)fg16, (const unsigned int*)xbc16, fb,
      (const float2*)cA, (const float2*)cS, (unsigned int*)gate16);
  // 5) out = gh @ W_out^T  (fp32 out)
  gemm_bt8<false, false, false><<<dim3(D_M / TN, NT / TM), 512, 0, stream>>>(
      gate16, Wout16, out, nullptr, nullptr, D_M, H_M);
}

// Round 10
// 553.666 us; speedup vs baseline: 1.8152x; 1.0778x over previous
//
#include <hip/hip_runtime.h>
#include <stdint.h>
#include <math.h>

#define N_B 4
#define T_S 4096
#define D_M 1024
#define H_M 1536
#define NT  (N_B * T_S)   // 16384
#define G2  (2 * H_M)     // 3072
#define LCH 32            // timesteps per chunk
#define NCH 128           // chunks (LCH*NCH == T_S)

typedef __attribute__((ext_vector_type(8))) short short8;
typedef __attribute__((ext_vector_type(4))) float floatx4;

__device__ __forceinline__ unsigned short f2bf(float f) {
  unsigned u = __float_as_uint(f);
  u += 0x7fff + ((u >> 16) & 1);            // RNE
  return (unsigned short)(u >> 16);
}
__device__ __forceinline__ float bf2f(unsigned short u) {
  return __uint_as_float(((unsigned)u) << 16);
}
__device__ __forceinline__ float bf_lo(unsigned p) { return __uint_as_float(p << 16); }
__device__ __forceinline__ float bf_hi(unsigned p) { return __uint_as_float(p & 0xffff0000u); }
__device__ __forceinline__ unsigned bf_pack(float lo, float hi) {
  return ((unsigned)f2bf(lo)) | (((unsigned)f2bf(hi)) << 16);
}
__device__ __forceinline__ float sigmoidf_(float x) { return 1.f / (1.f + __expf(-x)); }
__device__ __forceinline__ float softplusf_(float x) {
  return (x > 20.f) ? x : log1pf(__expf(x));
}
__device__ __forceinline__ float geluf_(float x) {
  return 0.5f * x * (1.f + erff(x * 0.70710678118654752f));
}

// ---------------- zero-fill fallback (diagnostic if ws_size too small) ----------------
__global__ void zero_out(float* __restrict__ out, int n) {
  int i = blockIdx.x * 256 + threadIdx.x;
  if (i < n) out[i] = 0.f;
}

// ---------------- fused f32 -> bf16 conversion of x, Win, Wg (one launch) ----------------
#define N4_X   (NT * D_M / 4)          // 4,194,304
#define N4_WIN (G2 * D_M / 4)          //   786,432
#define N4_WG  (G2 * H_M / 4)          // 1,179,648
__global__ void cvt3_bf16(const float* __restrict__ x, unsigned short* __restrict__ x16,
                          const float* __restrict__ win, unsigned short* __restrict__ win16,
                          const float* __restrict__ wg, unsigned short* __restrict__ wg16) {
  int i = blockIdx.x * 256 + threadIdx.x;
  const float* in; unsigned short* out;
  if (i < N4_X)                { in = x;   out = x16; }
  else if (i < N4_X + N4_WIN)  { in = win; out = win16; i -= N4_X; }
  else if (i < N4_X + N4_WIN + N4_WG) { in = wg; out = wg16; i -= N4_X + N4_WIN; }
  else return;
  float4 v = ((const float4*)in)[i];
  ushort4 o;
  o.x = f2bf(v.x); o.y = f2bf(v.y); o.z = f2bf(v.z); o.w = f2bf(v.w);
  ((ushort4*)out)[i] = o;
}

__global__ void cvt_bf16(const float* __restrict__ in, unsigned short* __restrict__ out, int n4) {
  int i = blockIdx.x * 256 + threadIdx.x;
  if (i >= n4) return;
  float4 v = ((const float4*)in)[i];
  ushort4 o;
  o.x = f2bf(v.x); o.y = f2bf(v.y); o.z = f2bf(v.z); o.w = f2bf(v.w);
  ((ushort4*)out)[i] = o;
}

// ---------------- bf16 MFMA GEMM, 256x256 tile, 4-phase k-half ring schedule ----------
// r2-VERBATIM (session best: GEMM2 149us @ MfmaUtil 46.7, 0 bank conflicts) -- FROZEN.
// Five schedule variants (ring / top-reads / deep-prefetch / A-global / m201-cadence)
// bracket 148-341us; this ring is the measured optimum of the family.
// C[m,n] = sum_k A[m,k]*B[n,k] (+bias[n]).  512 threads = 8 waves (2 Mx4 N), BK=64.
// LDS 64 KiB ring of 4 k-half slots: [A.kh0][A.kh1][B.kh0][B.kh1], each [256 rows x 32 k].
// Phases per tile = (khalf, nhalf), 16 MFMA each; A-frags (8) read once per khalf and
// register-held across both n-phases; B-frags (2) read per phase.
// Slot lifetimes: A.kh0 last read P1, restaged (t+1) at P2; B.kh0 last read P2, restaged P3;
// A.kh1 last read P3, restaged P4; B.kh1 last read P4, restaged next P1. Stage issues always
// come AFTER the post-MFMA barrier of the slot's last reading phase -> no write/read race.
// Counted waits (per-thread ledger, 2 loads per stage unit, 8 outstanding max):
//   P1: issue B.kh1(t); vmcnt(4) -> A.kh0(t),B.kh0(t) landed (issued 3 phases earlier)
//   P3: issue B.kh0(t+1); vmcnt(4) -> A.kh1(t),B.kh1(t) landed (2-3 phases earlier)
// Never drains in main loop; vmcnt(0) only at final tile's P3. Raw s_barrier (6/tile),
// s_setprio(1) around MFMA clusters (T5).
// Bank swizzle (0 conflicts measured): phys slot = kq ^ ((fr>>1)&3) on reads; global
// source pre-swizzled g=(tid&3)^((tid>>3)&3) with linear LDS dest (rule #21).
// XCD swizzle (r1-proven: FETCH 234->141 MB): bijective, nwg%8==0 for all shapes.
#define TM 256
#define TN 256

__device__ __forceinline__ void stage16(const unsigned short* g, unsigned short* l) {
  __builtin_amdgcn_global_load_lds((__attribute__((address_space(1))) void*)g,
                                   (__attribute__((address_space(3))) void*)l, 16, 0, 0);
}

template<bool BIAS, bool OUT_BF16, bool SPLIT>
__global__ __launch_bounds__(512, 2)
void gemm_bt8(const unsigned short* __restrict__ A,
              const unsigned short* __restrict__ B,
              void* __restrict__ Cv, void* __restrict__ Cv2,
              const float* __restrict__ bias,
              int N, int K) {
  // ring slots: 0=A.kh0, 1=A.kh1, 2=B.kh0, 3=B.kh1 ; each 256x32 bf16 = 16 KB
  __shared__ __align__(16) unsigned short lds[4][8192];
  const int tid  = threadIdx.x;
  const int lane = tid & 63;
  const int wave = tid >> 6;
  const int wr = wave >> 2;                  // 0..1  (M half of tile)
  const int wc = wave & 3;                   // 0..3  (N quarter of tile)

  // bijective XCD-aware block swizzle (nwg % 8 == 0 for all shapes used)
  const int gx  = gridDim.x;
  const int nwg = gx * gridDim.y;
  const int bid = blockIdx.y * gx + blockIdx.x;
  const int cpx = nwg >> 3;
  const int swz = (bid & 7) * cpx + (bid >> 3);
  const int bm = (swz / gx) * TM;
  const int bn = (swz % gx) * TN;

  floatx4 acc[8][4];
#pragma unroll
  for (int i = 0; i < 8; i++)
#pragma unroll
    for (int j = 0; j < 4; j++)
      acc[i][j] = (floatx4){0.f, 0.f, 0.f, 0.f};

  // ---- staging: one k-half unit = 256 rows x 32 k = 1024 x 16B chunks; thread does 2.
  // chunk c = tid + 512u -> row r = c>>2 (= tid>>2 + 128u), phys slot sl = c&3.
  // logical k-group fetched: g = sl ^ ((r>>1)&3) = (tid&3) ^ ((tid>>3)&3)  (u-invariant).
  const int r0_ = tid >> 2;                  // 0..127
  const int g8  = ((tid & 3) ^ ((tid >> 3) & 3)) * 8;
  const unsigned short* Ag1 = A + (size_t)(bm + r0_)       * K + g8;
  const unsigned short* Ag2 = A + (size_t)(bm + r0_ + 128) * K + g8;
  const unsigned short* Bg1 = B + (size_t)(bn + r0_)       * K + g8;
  const unsigned short* Bg2 = B + (size_t)(bn + r0_ + 128) * K + g8;
  const int ld1 = tid * 8;                   // elem offset in slot
  const int ld2 = ld1 + 4096;

#define STAGE_A(kh, kb) do { \
    stage16(Ag1 + (kb) + (kh) * 32, &lds[kh][ld1]); \
    stage16(Ag2 + (kb) + (kh) * 32, &lds[kh][ld2]); } while (0)
#define STAGE_B(kh, kb) do { \
    stage16(Bg1 + (kb) + (kh) * 32, &lds[2 + (kh)][ld1]); \
    stage16(Bg2 + (kb) + (kh) * 32, &lds[2 + (kh)][ld2]); } while (0)

  // ---- fragment read bases: lane (fr, kq); phys slot = kq ^ ((fr>>1)&3)
  const int fr = lane & 15;
  const int kq = lane >> 4;
  const int sx = (kq ^ ((fr >> 1) & 3)) * 8;
  const int abase = (wr * 128 + fr) * 32 + sx;   // + i*512
  const int bbase = (wc * 64 + fr) * 32 + sx;    // + j*512

  const int nt = K >> 6;
  short8 af[8], bfr[2];

  // prologue: issue A.kh0(0), B.kh0(0), A.kh1(0) -- matches steady-state ledger order
  STAGE_A(0, 0); STAGE_B(0, 0); STAGE_A(1, 0);

  for (int t = 0; t < nt; ++t) {
    const int k0 = t << 6;
    const int kn = k0 + 64;
    const bool st = (t + 1 < nt);

    // ---- P1: (kh0, n01) ----
    STAGE_B(1, k0);                                  // B.kh1(t) -> slot 3
    asm volatile("s_waitcnt vmcnt(4)" ::: "memory"); // A.kh0(t), B.kh0(t) landed
    __builtin_amdgcn_s_barrier();
#pragma unroll
    for (int i = 0; i < 8; ++i) af[i]  = *(const short8*)(&lds[0][abase + i * 512]);
#pragma unroll
    for (int j = 0; j < 2; ++j) bfr[j] = *(const short8*)(&lds[2][bbase + j * 512]);
    __builtin_amdgcn_s_setprio(1);
#pragma unroll
    for (int i = 0; i < 8; ++i)
#pragma unroll
      for (int j = 0; j < 2; ++j)
        acc[i][j] = __builtin_amdgcn_mfma_f32_16x16x32_bf16(af[i], bfr[j], acc[i][j], 0, 0, 0);
    __builtin_amdgcn_s_setprio(0);
    __builtin_amdgcn_s_barrier();

    // ---- P2: (kh0, n23), A-frags reused ----
    if (st) STAGE_A(0, kn);                          // A.kh0(t+1) -> slot 0
#pragma unroll
    for (int j = 0; j < 2; ++j) bfr[j] = *(const short8*)(&lds[2][bbase + 1024 + j * 512]);
    __builtin_amdgcn_s_setprio(1);
#pragma unroll
    for (int i = 0; i < 8; ++i)
#pragma unroll
      for (int j = 0; j < 2; ++j)
        acc[i][2 + j] = __builtin_amdgcn_mfma_f32_16x16x32_bf16(af[i], bfr[j], acc[i][2 + j], 0, 0, 0);
    __builtin_amdgcn_s_setprio(0);
    __builtin_amdgcn_s_barrier();

    // ---- P3: (kh1, n01) ----
    if (st) STAGE_B(0, kn);                          // B.kh0(t+1) -> slot 2
    if (st) { asm volatile("s_waitcnt vmcnt(4)" ::: "memory"); }  // A.kh1(t), B.kh1(t)
    else    { asm volatile("s_waitcnt vmcnt(0)" ::: "memory"); }
    __builtin_amdgcn_s_barrier();
#pragma unroll
    for (int i = 0; i < 8; ++i) af[i]  = *(const short8*)(&lds[1][abase + i * 512]);
#pragma unroll
    for (int j = 0; j < 2; ++j) bfr[j] = *(const short8*)(&lds[3][bbase + j * 512]);
    __builtin_amdgcn_s_setprio(1);
#pragma unroll
    for (int i = 0; i < 8; ++i)
#pragma unroll
      for (int j = 0; j < 2; ++j)
        acc[i][j] = __builtin_amdgcn_mfma_f32_16x16x32_bf16(af[i], bfr[j], acc[i][j], 0, 0, 0);
    __builtin_amdgcn_s_setprio(0);
    __builtin_amdgcn_s_barrier();

    // ---- P4: (kh1, n23), A-frags reused ----
    if (st) STAGE_A(1, kn);                          // A.kh1(t+1) -> slot 1
#pragma unroll
    for (int j = 0; j < 2; ++j) bfr[j] = *(const short8*)(&lds[3][bbase + 1024 + j * 512]);
    __builtin_amdgcn_s_setprio(1);
#pragma unroll
    for (int i = 0; i < 8; ++i)
#pragma unroll
      for (int j = 0; j < 2; ++j)
        acc[i][2 + j] = __builtin_amdgcn_mfma_f32_16x16x32_bf16(af[i], bfr[j], acc[i][2 + j], 0, 0, 0);
    __builtin_amdgcn_s_setprio(0);
    __builtin_amdgcn_s_barrier();
  }
#undef STAGE_A
#undef STAGE_B

  // C/D layout (m89-verified): col = lane&15, row = (lane>>4)*4 + reg
  // stores row-major (j innermost): 64B C-line halves issued back-to-back (r2-proven,
  // WRITE_SIZE == output size).
  const int half  = SPLIT ? (N >> 1) : N;
  const bool hi   = SPLIT && (bn >= half);
  void* Cb        = hi ? Cv2 : Cv;
  const int coff  = hi ? half : 0;
  const int cn = lane & 15;
  const int rb = (lane >> 4) * 4;
  float bv[4];
#pragma unroll
  for (int j = 0; j < 4; ++j)
    bv[j] = BIAS ? bias[bn + wc * 64 + j * 16 + cn] : 0.f;
  const int col0 = bn + wc * 64 + cn - coff;
#pragma unroll
  for (int i = 0; i < 8; ++i) {
    const int row0 = bm + wr * 128 + i * 16 + rb;
#pragma unroll
    for (int r = 0; r < 4; ++r) {
      const size_t rowb = (size_t)(row0 + r) * half + col0;
#pragma unroll
      for (int j = 0; j < 4; ++j) {
        float v = acc[i][j][r] + bv[j];
        if (OUT_BF16) ((unsigned short*)Cb)[rowb + j * 16] = f2bf(v);
        else          ((float*)Cb)[rowb + j * 16] = v;
      }
    }
  }
}

// ---------------- depthwise causal conv (K=4) + bias, STRIP form ----------------------
// r9-proven (part of the -48us tail win). Each thread produces 8 consecutive timesteps
// for 2 channels with a rolling 4-tap window: 11 loads / 8 stores, fully unrolled.
#define CT 8   // timesteps per thread
__global__ void conv_dw(const unsigned int* __restrict__ xbpre2, const float* __restrict__ cw,
                        const float* __restrict__ cb, unsigned int* __restrict__ xbc2) {
  int i0 = blockIdx.x * 256 + threadIdx.x;       // pair index, 0..H_M/2-1
  int t0 = blockIdx.y * CT;
  size_t nt = (size_t)blockIdx.z * T_S + t0;
  const int h = 2 * i0;
  const float4 wa = ((const float4*)cw)[h];      // taps for channel h
  const float4 wb = ((const float4*)cw)[h + 1];  // taps for channel h+1
  const float2 cb2 = ((const float2*)cb)[i0];
  size_t base = nt * (H_M / 2) + i0;
  // rolling window (zeros before t=0, causal)
  float xm1a = 0.f, xm1b = 0.f, xm2a = 0.f, xm2b = 0.f, xm3a = 0.f, xm3b = 0.f;
  if (t0 >= 1) { unsigned p = xbpre2[base - (size_t)(H_M / 2)];
    xm1a = bf_lo(p); xm1b = bf_hi(p); }
  if (t0 >= 2) { unsigned p = xbpre2[base - 2 * (size_t)(H_M / 2)];
    xm2a = bf_lo(p); xm2b = bf_hi(p); }
  if (t0 >= 3) { unsigned p = xbpre2[base - 3 * (size_t)(H_M / 2)];
    xm3a = bf_lo(p); xm3b = bf_hi(p); }
#pragma unroll
  for (int s = 0; s < CT; ++s) {
    unsigned p0 = xbpre2[base + (size_t)s * (H_M / 2)];
    float xa = bf_lo(p0), xb = bf_hi(p0);
    float aa = cb2.x + wa.w * xa + wa.z * xm1a + wa.y * xm2a + wa.x * xm3a;
    float ab = cb2.y + wb.w * xb + wb.z * xm1b + wb.y * xm2b + wb.x * xm3b;
    xbc2[base + (size_t)s * (H_M / 2)] = bf_pack(aa, ab);
    xm3a = xm2a; xm2a = xm1a; xm1a = xa;
    xm3b = xm2b; xm2b = xm1b; xm1b = xb;
  }
}

// ---------------- chunked linear scan (2 channels/thread) ----------------
// scan_A: per-chunk summaries (A = prod alpha, S = local scan end state).
__global__ void scan_A(const unsigned int* __restrict__ fg2, const unsigned int* __restrict__ xbc2,
                       const float* __restrict__ fb,
                       float2* __restrict__ cA2, float2* __restrict__ cS2) {
  int i0 = blockIdx.x * 256 + threadIdx.x;       // pair index
  int ch = blockIdx.y;
  int n = blockIdx.z;
  const float2 fb2 = ((const float2*)fb)[i0];
  const float c8a = 8.f * softplusf_(fb2.x);
  const float c8b = 8.f * softplusf_(fb2.y);
  float apa = 1.f, sa = 0.f, apb = 1.f, sb = 0.f;
  size_t r = (size_t)n * T_S + (size_t)ch * LCH;
#pragma unroll 4
  for (int i = 0; i < LCH; i++, r++) {
    unsigned pf = fg2[r * (G2 / 2) + i0];
    unsigned pi = fg2[r * (G2 / 2) + H_M / 2 + i0];
    unsigned px = xbc2[r * (H_M / 2) + i0];
    float alpha_a = __expf(-c8a * sigmoidf_(bf_lo(pf)));
    float alpha_b = __expf(-c8b * sigmoidf_(bf_hi(pf)));
    float beta_a = sqrtf(1.f - alpha_a * alpha_a + 1e-6f);
    float beta_b = sqrtf(1.f - alpha_b * alpha_b + 1e-6f);
    sa = alpha_a * sa + beta_a * sigmoidf_(bf_lo(pi)) * bf_lo(px);
    sb = alpha_b * sb + beta_b * sigmoidf_(bf_hi(pi)) * bf_hi(px);
    apa *= alpha_a;
    apb *= alpha_b;
  }
  size_t o = ((size_t)n * NCH + ch) * (H_M / 2) + i0;
  cA2[o] = make_float2(apa, apb);
  cS2[o] = make_float2(sa, sb);
}

// scan_B (new, r10): exclusive-prefix carry per (n, channel-pair) over chunk summaries,
// written IN-PLACE over cA (read-before-write per element; bitwise-identical op order to
// the old per-block prescan). Removes scan_C's O(NCH^2) redundant prescan (1536 blocks x
// avg-64 serial L2 iterations, ~390 MB aggregate L2 reads).
__global__ void scan_B(float2* __restrict__ cAio, const float2* __restrict__ cS2) {
  int i0 = blockIdx.x * 256 + threadIdx.x;       // pair index, 0..H_M/2-1
  int n = blockIdx.y;
  float sa = 0.f, sb = 0.f;
#pragma unroll 4
  for (int c = 0; c < NCH; ++c) {
    size_t o = ((size_t)n * NCH + c) * (H_M / 2) + i0;
    float2 a = cAio[o];
    float2 s = cS2[o];
    cAio[o] = make_float2(sa, sb);               // exclusive prefix (carry-in for chunk c)
    sa = a.x * sa + s.x;
    sb = a.y * sb + s.y;
  }
}

// scan_C: replay with carry-in read directly (no prescan), fused gelu(gate)*h in-place.
__global__ void scan_C(const unsigned int* __restrict__ fg2, const unsigned int* __restrict__ xbc2,
                       const float* __restrict__ fb,
                       const float2* __restrict__ carry2,
                       unsigned int* gateh2) {
  int i0 = blockIdx.x * 256 + threadIdx.x;
  int ch = blockIdx.y;
  int n = blockIdx.z;
  const float2 fb2 = ((const float2*)fb)[i0];
  const float c8a = 8.f * softplusf_(fb2.x);
  const float c8b = 8.f * softplusf_(fb2.y);
  float2 cin = carry2[((size_t)n * NCH + ch) * (H_M / 2) + i0];
  float sa = cin.x, sb = cin.y;
  size_t r = (size_t)n * T_S + (size_t)ch * LCH;
#pragma unroll 4
  for (int i = 0; i < LCH; i++, r++) {
    unsigned pf = fg2[r * (G2 / 2) + i0];
    unsigned pi = fg2[r * (G2 / 2) + H_M / 2 + i0];
    unsigned px = xbc2[r * (H_M / 2) + i0];
    float alpha_a = __expf(-c8a * sigmoidf_(bf_lo(pf)));
    float alpha_b = __expf(-c8b * sigmoidf_(bf_hi(pf)));
    float beta_a = sqrtf(1.f - alpha_a * alpha_a + 1e-6f);
    float beta_b = sqrtf(1.f - alpha_b * alpha_b + 1e-6f);
    sa = alpha_a * sa + beta_a * sigmoidf_(bf_lo(pi)) * bf_lo(px);
    sb = alpha_b * sb + beta_b * sigmoidf_(bf_hi(pi)) * bf_hi(px);
    unsigned pg = gateh2[r * (H_M / 2) + i0];
    gateh2[r * (H_M / 2) + i0] = bf_pack(geluf_(bf_lo(pg)) * sa, geluf_(bf_hi(pg)) * sb);
  }
}

// ---------------- launcher ----------------
// Workspace layout (S = NT*H_M*2 = 50,331,648 B; peak = 4S + 9.4 MB ≈ 210.8 MB):
//   [0,S)    gate16 (GEMM1 out, lo half) -> scan_C in-place -> gh16 (GEMM3 A)
//   [S,2S)   xbpre16 (GEMM1 out, hi half; conv in; dead after conv)
//   [S,3S)   fg16 (GEMM2 out, overwrites xbpre16 + x16/Win16)
//   [2S,..)  x16 (33.6MB) + Win16 (6.3MB), live only during GEMM1
//   [3S,4S)  xbc16 (conv out; dead after scan_C)
//   [4S,..)  Wg16 (9.4MB, dead after GEMM2) aliased by cA(3.1) + cS(3.1) + Wout16(3.1)
//            (NCH=128: 6.29+3.15 MB fits the 9.44 MB region; cA becomes carries in-place)
extern "C" void kernel_launch(void* const* d_in, const int* in_sizes, int n_in,
                              void* d_out, int out_size, void* d_ws, size_t ws_size,
                              hipStream_t stream) {
  const float* x    = (const float*)d_in[0];
  const float* Win  = (const float*)d_in[1];
  const float* cw   = (const float*)d_in[2];
  const float* cb   = (const float*)d_in[3];
  const float* Wg   = (const float*)d_in[4];
  const float* bg   = (const float*)d_in[5];
  const float* fb   = (const float*)d_in[6];
  const float* Wout = (const float*)d_in[7];
  float* out = (float*)d_out;
  (void)in_sizes; (void)n_in;

  const size_t S = (size_t)NT * H_M * 2;
  const size_t needed = 4 * S + (size_t)G2 * H_M * 2;
  if (ws_size < needed) {
    zero_out<<<(out_size + 255) / 256, 256, 0, stream>>>(out, out_size);
    return;
  }

  char* base = (char*)d_ws;
  unsigned short* gate16  = (unsigned short*)(base);            // becomes gh16 in-place
  unsigned short* xbpre16 = (unsigned short*)(base + S);
  unsigned short* fg16    = (unsigned short*)(base + S);        // [S,3S) after conv
  unsigned short* x16     = (unsigned short*)(base + 2 * S);    // live during GEMM1 only
  unsigned short* Win16   = (unsigned short*)(base + 2 * S + (size_t)NT * D_M * 2);
  unsigned short* xbc16   = (unsigned short*)(base + 3 * S);
  unsigned short* Wg16    = (unsigned short*)(base + 4 * S);    // dead after GEMM2
  float* cA    = (float*)(base + 4 * S);                        // aliases Wg16 (after GEMM2)
  float* cS    = cA + (size_t)N_B * NCH * H_M;
  unsigned short* Wout16  = (unsigned short*)(cS + (size_t)N_B * NCH * H_M);

  // fused bf16 conversions (x, Win, Wg)
  cvt3_bf16<<<(N4_X + N4_WIN + N4_WG + 255) / 256, 256, 0, stream>>>(
      x, x16, Win, Win16, Wg, Wg16);

  // 1) gx = x @ W_in^T, single dispatch, split output: gate16 | xbpre16
  gemm_bt8<false, true, true><<<dim3(G2 / TN, NT / TM), 512, 0, stream>>>(
      x16, Win16, gate16, xbpre16, nullptr, G2, D_M);
  // 2) depthwise causal conv -> xbc16 (strip form, 8 t/thread)
  conv_dw<<<dim3(H_M / 512, T_S / CT, N_B), 256, 0, stream>>>(
      (const unsigned int*)xbpre16, cw, cb, (unsigned int*)xbc16);
  // 3) fg = xbc @ W_g^T + b_g  (overwrites xbpre16/x16/Win16 region)
  gemm_bt8<true, true, false><<<dim3(G2 / TN, NT / TM), 512, 0, stream>>>(
      xbc16, Wg16, fg16, nullptr, bg, G2, H_M);
  // Wout cvt into the now-dead Wg16 slot (after cA/cS)
  cvt_bf16<<<(D_M * H_M / 4 + 255) / 256, 256, 0, stream>>>(Wout, Wout16, D_M * H_M / 4);
  // 4) chunked linear scan: summaries -> carries (in-place over cA) -> fused replay
  scan_A<<<dim3(H_M / 512, NCH, N_B), 256, 0, stream>>>(
      (const unsigned int*)fg16, (const unsigned int*)xbc16, fb, (float2*)cA, (float2*)cS);
  scan_B<<<dim3(H_M / 512, N_B), 256, 0, stream>>>((float2*)cA, (const float2*)cS);
  scan_C<<<dim3(H_M / 512, NCH, N_B), 256, 0, stream>>>(
      (const unsigned int*)fg16, (const unsigned int*)xbc16, fb,
      (const float2*)cA, (unsigned int*)gate16);
  // 5) out = gh @ W_out^T  (fp32 out)
  gemm_bt8<false, false, false><<<dim3(D_M / TN, NT / TM), 512, 0, stream>>>(
      gate16, Wout16, out, nullptr, nullptr, D_M, H_M);
}